// Round 6
// baseline (159.711 us; speedup 1.0000x reference)
//
#include <hip/hip_runtime.h>
#include <hip/hip_bf16.h>

// Shapes: B=2, L=2048, D_IN=1024, D_OUT=1024, H=16, HD=64
// Pipeline:
//   cvt_all: x -> xb; [Wq*c, Wg, Wk] -> w3; Wv -> wvb; Wo -> wob  (c = 0.125*log2e in Wq)
//   proj:   QGK[4096,3072] = xb @ w3^T  and  VT[1024,4096] = wvb @ xb^T  (one dispatch)
//   attn:   flash attention; block = 1 q-tile x 2 kv-half waves; K double-buffered in LDS
//           (global_load_lds, counted vmcnt); V -> registers from VT (L2); fixed-max exp2
//           softmax; swapped QK^T; ones-MFMA row sums; descending-qt LPT dispatch.
//   gemm<true,64>: out[4096,1024](fp32) = ctx @ Wo^T + bo

typedef __bf16 v8bf __attribute__((ext_vector_type(8)));
typedef __bf16 v4bf __attribute__((ext_vector_type(4)));
typedef float  v4f  __attribute__((ext_vector_type(4)));

using gas_void = const __attribute__((address_space(1))) void*;
using las_void = __attribute__((address_space(3))) void*;

__device__ __forceinline__ void async_ld16(const void* g, void* l) {
  __builtin_amdgcn_global_load_lds((gas_void)g, (las_void)l, 16, 0, 0);
}
__device__ __forceinline__ float fexp2(float x) { return __builtin_amdgcn_exp2f(x); }

#define QSCALE 0.18033688011112042f  /* 0.125 * log2(e) */
#define LOG2E  1.4426950408889634f
#define FIXMAX 8.0f                   /* fixed softmax max in exp2 domain */

// ---------------- all fp32 -> bf16 conversions in one kernel ----------------
__global__ void cvt_all_kernel(const float* __restrict__ x,  const float* __restrict__ Wq,
                               const float* __restrict__ Wg, const float* __restrict__ Wk,
                               const float* __restrict__ Wv, const float* __restrict__ Wo,
                               __bf16* __restrict__ xb, __bf16* __restrict__ w3,
                               __bf16* __restrict__ wvb, __bf16* __restrict__ wob) {
  int i = blockIdx.x * 256 + threadIdx.x;  // float4 index; total 2359296
  const float* s; v4bf* d; int j; float sc = 1.f;
  if (i < 1048576)      { s = x;  d = (v4bf*)xb;           j = i; }
  else if (i < 1310720) { s = Wq; d = (v4bf*)w3;           j = i - 1048576; sc = QSCALE; }
  else if (i < 1572864) { s = Wg; d = (v4bf*)w3 + 262144;  j = i - 1310720; }
  else if (i < 1835008) { s = Wk; d = (v4bf*)w3 + 524288;  j = i - 1572864; }
  else if (i < 2097152) { s = Wv; d = (v4bf*)wvb;          j = i - 1835008; }
  else                  { s = Wo; d = (v4bf*)wob;          j = i - 2097152; }
  float4 v = reinterpret_cast<const float4*>(s)[j];
  v4bf o;
  o[0] = (__bf16)(v.x * sc); o[1] = (__bf16)(v.y * sc);
  o[2] = (__bf16)(v.z * sc); o[3] = (__bf16)(v.w * sc);
  d[j] = o;
}

// ---------------- bf16 B^T GEMM tile (m97-style), as device function ----------------
// C[m0:m0+128, n0:n0+BN] = A[m0:,:K] * B[n0:,:K]^T
template<bool OUTF32, int BN>
__device__ __forceinline__ void gemm_tile(
    const __bf16* __restrict__ A, const __bf16* __restrict__ B,
    void* __restrict__ C, const float* __restrict__ bias,
    int K, int lda, int ldb, int ldc, int m0, int n0,
    __bf16* As, __bf16* Bs) {
  constexpr int NI = BN / 32;
  const int tid  = threadIdx.x;
  const int w    = tid >> 6;
  const int lane = tid & 63;
  const int fr   = lane & 15;
  const int fq   = lane >> 4;
  const int srow = lane >> 2;
  const int scol = lane & 3;
  const int wr = (w >> 1) * 64, wc = (w & 1) * (BN / 2);

  v4f acc[4][NI];
#pragma unroll
  for (int i = 0; i < 4; ++i)
#pragma unroll
    for (int j = 0; j < NI; ++j)
#pragma unroll
      for (int r = 0; r < 4; ++r) acc[i][j][r] = 0.f;

  for (int k0 = 0; k0 < K; k0 += 32) {
#pragma unroll
    for (int i = 0; i < 2; ++i) {
      const int c = w + i * 4;
      async_ld16(A + (size_t)(m0 + c * 16 + srow) * lda + k0 + scol * 8, (void*)(As + c * 512));
    }
#pragma unroll
    for (int i = 0; i < BN / 64; ++i) {
      const int c = w + i * 4;
      async_ld16(B + (size_t)(n0 + c * 16 + srow) * ldb + k0 + scol * 8, (void*)(Bs + c * 512));
    }
    __syncthreads();

    v8bf a[4], b[NI];
#pragma unroll
    for (int mi = 0; mi < 4; ++mi)
      a[mi] = *reinterpret_cast<const v8bf*>(As + (wr + mi * 16 + fr) * 32 + fq * 8);
#pragma unroll
    for (int ni = 0; ni < NI; ++ni)
      b[ni] = *reinterpret_cast<const v8bf*>(Bs + (wc + ni * 16 + fr) * 32 + fq * 8);
#pragma unroll
    for (int mi = 0; mi < 4; ++mi)
#pragma unroll
      for (int ni = 0; ni < NI; ++ni)
        acc[mi][ni] = __builtin_amdgcn_mfma_f32_16x16x32_bf16(a[mi], b[ni], acc[mi][ni], 0, 0, 0);
    __syncthreads();
  }

#pragma unroll
  for (int mi = 0; mi < 4; ++mi)
#pragma unroll
    for (int ni = 0; ni < NI; ++ni)
#pragma unroll
      for (int r = 0; r < 4; ++r) {
        const int row = m0 + wr + mi * 16 + fq * 4 + r;
        const int col = n0 + wc + ni * 16 + fr;
        const float v = acc[mi][ni][r];
        if (OUTF32) {
          reinterpret_cast<float*>(C)[(size_t)row * ldc + col] = v + bias[col];
        } else {
          reinterpret_cast<__bf16*>(C)[(size_t)row * ldc + col] = (__bf16)v;
        }
      }
}

// merged projection: blocks 0..767 -> QGK = xb @ w3^T ; 768..1023 -> VT = wvb @ xb^T
__global__ __launch_bounds__(256) void proj_kernel(
    const __bf16* __restrict__ xb, const __bf16* __restrict__ w3,
    const __bf16* __restrict__ wvb, __bf16* __restrict__ qgk, __bf16* __restrict__ vt) {
  __shared__ __bf16 As[128 * 32];
  __shared__ __bf16 Bs[128 * 32];
  const int bid = blockIdx.x;
  if (bid < 768) {
    gemm_tile<false, 128>(xb, w3, (void*)qgk, nullptr, 1024, 1024, 1024, 3072,
                          (bid / 24) * 128, (bid % 24) * 128, As, Bs);
  } else {
    const int t = bid - 768;
    gemm_tile<false, 128>(wvb, xb, (void*)vt, nullptr, 1024, 1024, 1024, 4096,
                          (t >> 5) * 128, (t & 31) * 128, As, Bs);
  }
}

template<bool OUTF32, int BN>
__global__ __launch_bounds__(256) void gemm_bt_kernel(
    const __bf16* __restrict__ A, const __bf16* __restrict__ B,
    void* __restrict__ C, const float* __restrict__ bias,
    int K, int lda, int ldb, int ldc) {
  __shared__ __bf16 As[128 * 32];
  __shared__ __bf16 Bs[BN * 32];
  gemm_tile<OUTF32, BN>(A, B, C, bias, K, lda, ldb, ldc,
                        blockIdx.y * 128, blockIdx.x * BN, As, Bs);
}

// ---------------- flash attention: 2-wave blocks, K in LDS, V in regs ----------------
// QGK: [B*L, 3072] bf16 (q scaled by QSCALE cols 0-1023, g 1024-2047, k 2048-3071)
// VT:  [1024, 4096] bf16 ; VT[h*64+d][b*2048+l]
// Block (bh, qt): one 32-row q-tile, waves = kv-halves of the 64-wide K-step.
// Descending-qt dispatch (LPT); bh in low 5 bits -> XCD = bh%8 clustering.
// K tile [64][64] double-buffered via global_load_lds with 16B-block XOR swizzle
// pre-applied on the global source; V fragments straight from VT (L2-resident).
__global__ __launch_bounds__(128, 4) void attn_kernel(
    const __bf16* __restrict__ QGK, const __bf16* __restrict__ VT,
    __bf16* __restrict__ CTX) {
  constexpr int LD = 3072, L = 2048;
  // LDS: [0,16384) K dbuf (2 x 8KB); [16384,21504) per-wave P [32][40] bf16
  __shared__ __align__(16) char lds[21504];
  const int w = threadIdx.x >> 6, lane = threadIdx.x & 63;
  const int fr = lane & 15, fq = lane >> 4;
  const int bid = blockIdx.x;
  const int qt = 63 - (bid >> 5);
  const int bh = bid & 31;
  const int b = bh >> 4, h = bh & 15, hb = h * 64;
  const int q0 = qt * 32;
  const int nkt = (qt >> 1) + 1;
  const __bf16* base  = QGK + (size_t)b * L * LD;
  const __bf16* vbase = VT + (size_t)hb * 4096 + (size_t)b * L;
  __bf16* pw = (__bf16*)(lds + 16384 + w * 2560);

  v8bf onev;
#pragma unroll
  for (int i = 0; i < 8; ++i) onev[i] = (__bf16)1.0f;

  // Q fragments (scaled via Wq); B-operand of swapped QK^T
  v8bf qf[2][2];
#pragma unroll
  for (int mi = 0; mi < 2; ++mi)
#pragma unroll
    for (int ks = 0; ks < 2; ++ks)
      qf[mi][ks] = *reinterpret_cast<const v8bf*>(
          base + (size_t)(q0 + mi * 16 + fr) * LD + hb + ks * 32 + fq * 8);

  v4f cacc[2][4], csum[2];
#pragma unroll
  for (int mi = 0; mi < 2; ++mi) {
#pragma unroll
    for (int r = 0; r < 4; ++r) csum[mi][r] = 0.f;
#pragma unroll
    for (int nf = 0; nf < 4; ++nf)
#pragma unroll
      for (int r = 0; r < 4; ++r) cacc[mi][nf][r] = 0.f;
  }

  // stage K tile (64 kv x 64 d) for K-step k0s into buffer bi; 4 loads/thread
  auto stage = [&](int bi, int k0s) {
    char* bf_ = (char*)lds + bi * 8192;
#pragma unroll
    for (int i = 0; i < 4; ++i) {
      const int slot = i * 128 + w * 64 + lane;
      const int r = slot >> 3;
      const int cc = ((slot & 7) ^ (r & 7)) * 8;  // pre-swizzled source col-block
      async_ld16(base + (size_t)(k0s + r) * LD + 2048 + hb + cc,
                 bf_ + (i * 128 + w * 64) * 16);
    }
  };

  stage(0, 0);
  for (int kt = 0; kt < nkt; ++kt) {
    const int k0 = kt * 64;
    const bool last = (kt == nkt - 1);
    // V fragments for THIS step first (so compiler's vf-wait won't drain the K prefetch)
    v8bf vf[4];
#pragma unroll
    for (int nf = 0; nf < 4; ++nf)
      vf[nf] = *reinterpret_cast<const v8bf*>(
          vbase + (size_t)(nf * 16 + fr) * 4096 + k0 + w * 32 + fq * 8);
    if (!last) {
      stage((kt + 1) & 1, k0 + 64);
      asm volatile("s_waitcnt vmcnt(8)" ::: "memory");  // drain K(kt); K(kt+1)+vf in flight
    } else {
      asm volatile("s_waitcnt vmcnt(4)" ::: "memory");  // drain K(kt); vf in flight
    }
    __builtin_amdgcn_s_barrier();
    __builtin_amdgcn_sched_barrier(0);

    if (!(last && !(qt & 1) && w == 1)) {  // even qt: upper kv-half fully masked at diag
      const __bf16* Kt = (const __bf16*)(lds + (kt & 1) * 8192);
      v8bf kf[2][2];
#pragma unroll
      for (int ks = 0; ks < 2; ++ks)
#pragma unroll
        for (int nj = 0; nj < 2; ++nj)
          kf[ks][nj] = *reinterpret_cast<const v8bf*>(
              Kt + (w * 32 + nj * 16 + fr) * 64 + (((ks * 4 + fq) ^ (fr & 7)) * 8));

      // S^T = K @ Q^T over this wave's 32-kv half: C[kv, q]
      v4f s[2][2];
#pragma unroll
      for (int mi = 0; mi < 2; ++mi)
#pragma unroll
        for (int nj = 0; nj < 2; ++nj)
#pragma unroll
          for (int r = 0; r < 4; ++r) s[mi][nj][r] = 0.f;
      __builtin_amdgcn_s_setprio(1);
#pragma unroll
      for (int ks = 0; ks < 2; ++ks)
#pragma unroll
        for (int mi = 0; mi < 2; ++mi)
#pragma unroll
          for (int nj = 0; nj < 2; ++nj)
            s[mi][nj] = __builtin_amdgcn_mfma_f32_16x16x32_bf16(
                kf[ks][nj], qf[mi][ks], s[mi][nj], 0, 0, 0);
      __builtin_amdgcn_s_setprio(0);

      // p = exp2(s - FIXMAX); packed P write into per-wave [32][40] tile
      const bool mask = last && (w == (qt & 1));
#pragma unroll
      for (int mi = 0; mi < 2; ++mi) {
        const int qrow = q0 + mi * 16 + fr;
#pragma unroll
        for (int nj = 0; nj < 2; ++nj) {
          const int kvb = k0 + w * 32 + nj * 16 + fq * 4;
          v4bf pk;
#pragma unroll
          for (int r = 0; r < 4; ++r) {
            float sv = s[mi][nj][r];
            if (mask && (kvb + r > qrow)) sv = -__builtin_inff();
            pk[r] = (__bf16)fexp2(sv - FIXMAX);
          }
          *reinterpret_cast<v4bf*>(pw + (mi * 16 + fr) * 40 + nj * 16 + fq * 4) = pk;
        }
      }

      // PV over the 32-kv half: ctx += P @ V ; row-sums += P @ ones
      v8bf pa[2];
#pragma unroll
      for (int mi = 0; mi < 2; ++mi)
        pa[mi] = *reinterpret_cast<const v8bf*>(pw + (mi * 16 + fr) * 40 + fq * 8);
      __builtin_amdgcn_s_setprio(1);
#pragma unroll
      for (int mi = 0; mi < 2; ++mi)
        csum[mi] = __builtin_amdgcn_mfma_f32_16x16x32_bf16(pa[mi], onev, csum[mi], 0, 0, 0);
#pragma unroll
      for (int nf = 0; nf < 4; ++nf)
#pragma unroll
        for (int mi = 0; mi < 2; ++mi)
          cacc[mi][nf] = __builtin_amdgcn_mfma_f32_16x16x32_bf16(pa[mi], vf[nf], cacc[mi][nf], 0, 0, 0);
      __builtin_amdgcn_s_setprio(0);
    }
    __builtin_amdgcn_sched_barrier(0);
    __builtin_amdgcn_s_barrier();
  }

  // ---- combine kv-halves (additive, exact under fixed max) + epilogue ----
  __syncthreads();
  float* comb = (float*)lds;  // K buffers dead
  if (w == 1) {
    float* slot = comb + lane * 41;
#pragma unroll
    for (int mi = 0; mi < 2; ++mi) {
#pragma unroll
      for (int nf = 0; nf < 4; ++nf)
#pragma unroll
        for (int r = 0; r < 4; ++r) slot[mi * 16 + nf * 4 + r] = cacc[mi][nf][r];
#pragma unroll
      for (int r = 0; r < 4; ++r) slot[32 + mi * 4 + r] = csum[mi][r];
    }
  }
  __syncthreads();
  if (w == 0) {
    const float* slot = comb + lane * 41;
#pragma unroll
    for (int mi = 0; mi < 2; ++mi) {
#pragma unroll
      for (int nf = 0; nf < 4; ++nf)
#pragma unroll
        for (int r = 0; r < 4; ++r) cacc[mi][nf][r] += slot[mi * 16 + nf * 4 + r];
#pragma unroll
      for (int r = 0; r < 4; ++r) csum[mi][r] += slot[32 + mi * 4 + r];
    }
    // normalize, sigmoid(g) gate, store ctx bf16
#pragma unroll
    for (int mi = 0; mi < 2; ++mi)
#pragma unroll
      for (int r = 0; r < 4; ++r) {
        const int grow = q0 + mi * 16 + fq * 4 + r;
        const float rl = 1.f / csum[mi][r];
#pragma unroll
        for (int nf = 0; nf < 4; ++nf) {
          const int col = hb + nf * 16 + fr;
          float v = cacc[mi][nf][r] * rl;
          const float gt = (float)base[(size_t)grow * LD + 1024 + col];
          v *= 1.f / (1.f + fexp2(-gt * LOG2E));
          CTX[((size_t)b * L + grow) * 1024 + col] = (__bf16)v;
        }
      }
  }
}

extern "C" void kernel_launch(void* const* d_in, const int* in_sizes, int n_in,
                              void* d_out, int out_size, void* d_ws, size_t ws_size,
                              hipStream_t stream) {
  const float* x  = (const float*)d_in[0];
  const float* Wq = (const float*)d_in[1];
  const float* Wg = (const float*)d_in[2];
  const float* Wk = (const float*)d_in[3];
  const float* Wv = (const float*)d_in[4];
  const float* Wo = (const float*)d_in[5];
  const float* bo = (const float*)d_in[6];

  char* ws = (char*)d_ws;
  __bf16* xb  = (__bf16*)(ws);                  //  8 MB  [4096,1024]
  __bf16* w3  = (__bf16*)(ws + (8u  << 20));    //  6 MB  [3072,1024]
  __bf16* wvb = (__bf16*)(ws + (14u << 20));    //  2 MB
  __bf16* wob = (__bf16*)(ws + (16u << 20));    //  2 MB
  __bf16* qgk = (__bf16*)(ws + (18u << 20));    // 24 MB  [4096,3072]
  __bf16* vt  = (__bf16*)(ws + (42u << 20));    //  8 MB  [1024,4096]
  __bf16* ctx = (__bf16*)(ws + (50u << 20));    //  8 MB  [4096,1024]

  cvt_all_kernel<<<dim3(9216), dim3(256), 0, stream>>>(x, Wq, Wg, Wk, Wv, Wo,
                                                       xb, w3, wvb, wob);

  // QGK (768 blocks) + VT (256 blocks) in one dispatch
  proj_kernel<<<dim3(1024), dim3(256), 0, stream>>>(xb, w3, wvb, qgk, vt);

  // flash attention + gate: 2048 blocks (64 qt desc x 32 bh), 128 threads
  attn_kernel<<<dim3(2048), dim3(128), 0, stream>>>(qgk, vt, ctx);

  // out = ctx @ Wo^T + bo : M=4096, N=1024, K=1024, fp32 (BN=64 -> 512 blocks)
  gemm_bt_kernel<true, 64><<<dim3(16, 32), dim3(256), 0, stream>>>(
      ctx, wob, d_out, bo, 1024, 1024, 1024, 1024);
}

// Round 8
// 135.641 us; speedup vs baseline: 1.1775x; 1.1775x over previous
//
#include <hip/hip_runtime.h>
#include <hip/hip_bf16.h>

// Shapes: B=2, L=2048, D_IN=1024, D_OUT=1024, H=16, HD=64
// Pipeline:
//   cvt_all: x -> xb; [Wq*c, Wg, Wk] -> w3; Wv -> wvb; Wo -> wob  (c = 0.125*log2e in Wq)
//   proj:   QGK[4096,3072] = xb @ w3^T  and  VT[1024,4096] = wvb @ xb^T  (one dispatch)
//   attn:   flash attention; block = q-tile pair {2g,2g+1} x kv-half waves;
//           K double-buffered in LDS (global_load_lds, counted vmcnt); V -> regs from VT;
//           fixed-max exp2 softmax; swapped QK^T; ones-MFMA row sums.
//           Grid = 1024 = exact residency (4 blocks/CU, 16 waves/CU); per-CU-slot
//           g = {k,15-k,16+k,31-k} -> uniform 66 steps per SIMD; XCD = bh%8 clustering.
//           K-loop closes with sched_barrier(0) BEFORE s_barrier (rounds 5/6 proven order;
//           swapping them (round 7) let LDS reads sink past the barrier -> race).
//   gemm<true,64>: out[4096,1024](fp32) = ctx @ Wo^T + bo

typedef __bf16 v8bf __attribute__((ext_vector_type(8)));
typedef __bf16 v4bf __attribute__((ext_vector_type(4)));
typedef float  v4f  __attribute__((ext_vector_type(4)));

using gas_void = const __attribute__((address_space(1))) void*;
using las_void = __attribute__((address_space(3))) void*;

__device__ __forceinline__ void async_ld16(const void* g, void* l) {
  __builtin_amdgcn_global_load_lds((gas_void)g, (las_void)l, 16, 0, 0);
}
__device__ __forceinline__ float fexp2(float x) { return __builtin_amdgcn_exp2f(x); }

#define QSCALE 0.18033688011112042f  /* 0.125 * log2(e) */
#define LOG2E  1.4426950408889634f
#define FIXMAX 8.0f                   /* fixed softmax max in exp2 domain */

// ---------------- all fp32 -> bf16 conversions in one kernel ----------------
__global__ void cvt_all_kernel(const float* __restrict__ x,  const float* __restrict__ Wq,
                               const float* __restrict__ Wg, const float* __restrict__ Wk,
                               const float* __restrict__ Wv, const float* __restrict__ Wo,
                               __bf16* __restrict__ xb, __bf16* __restrict__ w3,
                               __bf16* __restrict__ wvb, __bf16* __restrict__ wob) {
  int i = blockIdx.x * 256 + threadIdx.x;  // float4 index; total 2359296
  const float* s; v4bf* d; int j; float sc = 1.f;
  if (i < 1048576)      { s = x;  d = (v4bf*)xb;           j = i; }
  else if (i < 1310720) { s = Wq; d = (v4bf*)w3;           j = i - 1048576; sc = QSCALE; }
  else if (i < 1572864) { s = Wg; d = (v4bf*)w3 + 262144;  j = i - 1310720; }
  else if (i < 1835008) { s = Wk; d = (v4bf*)w3 + 524288;  j = i - 1572864; }
  else if (i < 2097152) { s = Wv; d = (v4bf*)wvb;          j = i - 1835008; }
  else                  { s = Wo; d = (v4bf*)wob;          j = i - 2097152; }
  float4 v = reinterpret_cast<const float4*>(s)[j];
  v4bf o;
  o[0] = (__bf16)(v.x * sc); o[1] = (__bf16)(v.y * sc);
  o[2] = (__bf16)(v.z * sc); o[3] = (__bf16)(v.w * sc);
  d[j] = o;
}

// ---------------- bf16 B^T GEMM tile (m97-style), as device function ----------------
template<bool OUTF32, int BN>
__device__ __forceinline__ void gemm_tile(
    const __bf16* __restrict__ A, const __bf16* __restrict__ B,
    void* __restrict__ C, const float* __restrict__ bias,
    int K, int lda, int ldb, int ldc, int m0, int n0,
    __bf16* As, __bf16* Bs) {
  constexpr int NI = BN / 32;
  const int tid  = threadIdx.x;
  const int w    = tid >> 6;
  const int lane = tid & 63;
  const int fr   = lane & 15;
  const int fq   = lane >> 4;
  const int srow = lane >> 2;
  const int scol = lane & 3;
  const int wr = (w >> 1) * 64, wc = (w & 1) * (BN / 2);

  v4f acc[4][NI];
#pragma unroll
  for (int i = 0; i < 4; ++i)
#pragma unroll
    for (int j = 0; j < NI; ++j)
#pragma unroll
      for (int r = 0; r < 4; ++r) acc[i][j][r] = 0.f;

  for (int k0 = 0; k0 < K; k0 += 32) {
#pragma unroll
    for (int i = 0; i < 2; ++i) {
      const int c = w + i * 4;
      async_ld16(A + (size_t)(m0 + c * 16 + srow) * lda + k0 + scol * 8, (void*)(As + c * 512));
    }
#pragma unroll
    for (int i = 0; i < BN / 64; ++i) {
      const int c = w + i * 4;
      async_ld16(B + (size_t)(n0 + c * 16 + srow) * ldb + k0 + scol * 8, (void*)(Bs + c * 512));
    }
    __syncthreads();

    v8bf a[4], b[NI];
#pragma unroll
    for (int mi = 0; mi < 4; ++mi)
      a[mi] = *reinterpret_cast<const v8bf*>(As + (wr + mi * 16 + fr) * 32 + fq * 8);
#pragma unroll
    for (int ni = 0; ni < NI; ++ni)
      b[ni] = *reinterpret_cast<const v8bf*>(Bs + (wc + ni * 16 + fr) * 32 + fq * 8);
#pragma unroll
    for (int mi = 0; mi < 4; ++mi)
#pragma unroll
      for (int ni = 0; ni < NI; ++ni)
        acc[mi][ni] = __builtin_amdgcn_mfma_f32_16x16x32_bf16(a[mi], b[ni], acc[mi][ni], 0, 0, 0);
    __syncthreads();
  }

#pragma unroll
  for (int mi = 0; mi < 4; ++mi)
#pragma unroll
    for (int ni = 0; ni < NI; ++ni)
#pragma unroll
      for (int r = 0; r < 4; ++r) {
        const int row = m0 + wr + mi * 16 + fq * 4 + r;
        const int col = n0 + wc + ni * 16 + fr;
        const float v = acc[mi][ni][r];
        if (OUTF32) {
          reinterpret_cast<float*>(C)[(size_t)row * ldc + col] = v + bias[col];
        } else {
          reinterpret_cast<__bf16*>(C)[(size_t)row * ldc + col] = (__bf16)v;
        }
      }
}

// merged projection: blocks 0..767 -> QGK = xb @ w3^T ; 768..1023 -> VT = wvb @ xb^T
__global__ __launch_bounds__(256) void proj_kernel(
    const __bf16* __restrict__ xb, const __bf16* __restrict__ w3,
    const __bf16* __restrict__ wvb, __bf16* __restrict__ qgk, __bf16* __restrict__ vt) {
  __shared__ __bf16 As[128 * 32];
  __shared__ __bf16 Bs[128 * 32];
  const int bid = blockIdx.x;
  if (bid < 768) {
    gemm_tile<false, 128>(xb, w3, (void*)qgk, nullptr, 1024, 1024, 1024, 3072,
                          (bid / 24) * 128, (bid % 24) * 128, As, Bs);
  } else {
    const int t = bid - 768;
    gemm_tile<false, 128>(wvb, xb, (void*)vt, nullptr, 1024, 1024, 1024, 4096,
                          (t >> 5) * 128, (t & 31) * 128, As, Bs);
  }
}

template<bool OUTF32, int BN>
__global__ __launch_bounds__(256) void gemm_bt_kernel(
    const __bf16* __restrict__ A, const __bf16* __restrict__ B,
    void* __restrict__ C, const float* __restrict__ bias,
    int K, int lda, int ldb, int ldc) {
  __shared__ __bf16 As[128 * 32];
  __shared__ __bf16 Bs[BN * 32];
  gemm_tile<OUTF32, BN>(A, B, C, bias, K, lda, ldb, ldc,
                        blockIdx.y * 128, blockIdx.x * BN, As, Bs);
}

// ---------------- flash attention: 4-wave blocks, K in LDS, V in regs ----------------
// QGK: [B*L, 3072] bf16 (q scaled by QSCALE cols 0-1023, g 1024-2047, k 2048-3071)
// VT:  [1024, 4096] bf16 ; VT[h*64+d][b*2048+l]
// Block (g, bh): q-tiles {2g, 2g+1}; waves tl=w>>1 (tile), hf=w&1 (kv-half); nkt=g+1.
// bid = u*256 + v ; bh = v&31 (XCD = bh%8, 4 bh/XCD); k = v>>5;
// g(u,k) = {k, 15-k, 16+k, 31-k}[u] -> per-CU-slot work uniform (66 steps total).
__global__ __launch_bounds__(256, 4) void attn_kernel(
    const __bf16* __restrict__ QGK, const __bf16* __restrict__ VT,
    __bf16* __restrict__ CTX) {
  constexpr int LD = 3072, L = 2048;
  // LDS: [0,16384) K dbuf (2 x 8KB); [16384,37888) per-wave P [32][40]bf16 / combine (union)
  __shared__ __align__(16) char lds[37888];
  const int w = threadIdx.x >> 6, lane = threadIdx.x & 63;
  const int fr = lane & 15, fq = lane >> 4;
  const int tl = w >> 1, hf = w & 1;
  const int u = blockIdx.x >> 8, v = blockIdx.x & 255;
  const int k = v >> 5;
  const int g = (u == 0) ? k : (u == 1) ? 15 - k : (u == 2) ? 16 + k : 31 - k;
  const int bh = v & 31;
  const int b = bh >> 4, h = bh & 15, hb = h * 64;
  const int qt = 2 * g + tl, q0 = qt * 32, nkt = g + 1;
  const __bf16* base  = QGK + (size_t)b * L * LD;
  const __bf16* vbase = VT + (size_t)hb * 4096 + (size_t)b * L;
  __bf16* pw = (__bf16*)(lds + 16384 + w * 2560);

  v8bf onev;
#pragma unroll
  for (int i = 0; i < 8; ++i) onev[i] = (__bf16)1.0f;

  // Q fragments (scaled via Wq); B-operand of swapped QK^T
  v8bf qf[2][2];
#pragma unroll
  for (int mi = 0; mi < 2; ++mi)
#pragma unroll
    for (int ks = 0; ks < 2; ++ks)
      qf[mi][ks] = *reinterpret_cast<const v8bf*>(
          base + (size_t)(q0 + mi * 16 + fr) * LD + hb + ks * 32 + fq * 8);

  v4f cacc[2][4], csum[2];
#pragma unroll
  for (int mi = 0; mi < 2; ++mi) {
#pragma unroll
    for (int r = 0; r < 4; ++r) csum[mi][r] = 0.f;
#pragma unroll
    for (int nf = 0; nf < 4; ++nf)
#pragma unroll
      for (int r = 0; r < 4; ++r) cacc[mi][nf][r] = 0.f;
  }

  // stage K tile (64 kv x 64 d) for K-step k0s into buffer bi; 2 loads/thread (256 thr)
  auto stage = [&](int bi, int k0s) {
    char* bf_ = (char*)lds + bi * 8192;
#pragma unroll
    for (int i = 0; i < 2; ++i) {
      const int slot = i * 256 + w * 64 + lane;
      const int r = slot >> 3;
      const int cc = ((slot & 7) ^ (r & 7)) * 8;  // pre-swizzled source col-block
      async_ld16(base + (size_t)(k0s + r) * LD + 2048 + hb + cc,
                 bf_ + (i * 256 + w * 64) * 16);
    }
  };

  stage(0, 0);
  for (int kt = 0; kt < nkt; ++kt) {
    const int k0 = kt * 64;
    const bool last = (kt == nkt - 1);
    // V fragments for this wave's kv-half (contiguous 16B from VT, L2-resident)
    v8bf vf[4];
#pragma unroll
    for (int nf = 0; nf < 4; ++nf)
      vf[nf] = *reinterpret_cast<const v8bf*>(
          vbase + (size_t)(nf * 16 + fr) * 4096 + k0 + hf * 32 + fq * 8);
    if (!last) {
      stage((kt + 1) & 1, k0 + 64);
      asm volatile("s_waitcnt vmcnt(6)" ::: "memory");  // drain K(kt); K(kt+1)+vf in flight
    } else {
      asm volatile("s_waitcnt vmcnt(4)" ::: "memory");  // drain K(kt); vf in flight
    }
    __builtin_amdgcn_s_barrier();
    __builtin_amdgcn_sched_barrier(0);

    if (!(last && tl == 0 && hf == 1)) {  // even tile: upper kv-half fully masked at diag
      const __bf16* Kt = (const __bf16*)(lds + (kt & 1) * 8192);
      v8bf kf[2][2];
#pragma unroll
      for (int ks = 0; ks < 2; ++ks)
#pragma unroll
        for (int nj = 0; nj < 2; ++nj)
          kf[ks][nj] = *reinterpret_cast<const v8bf*>(
              Kt + (hf * 32 + nj * 16 + fr) * 64 + (((ks * 4 + fq) ^ (fr & 7)) * 8));

      // S^T = K @ Q^T over this wave's 32-kv half: C[kv, q]
      v4f s[2][2];
#pragma unroll
      for (int mi = 0; mi < 2; ++mi)
#pragma unroll
        for (int nj = 0; nj < 2; ++nj)
#pragma unroll
          for (int r = 0; r < 4; ++r) s[mi][nj][r] = 0.f;
      __builtin_amdgcn_s_setprio(1);
#pragma unroll
      for (int ks = 0; ks < 2; ++ks)
#pragma unroll
        for (int mi = 0; mi < 2; ++mi)
#pragma unroll
          for (int nj = 0; nj < 2; ++nj)
            s[mi][nj] = __builtin_amdgcn_mfma_f32_16x16x32_bf16(
                kf[ks][nj], qf[mi][ks], s[mi][nj], 0, 0, 0);
      __builtin_amdgcn_s_setprio(0);

      // p = exp2(s - FIXMAX); packed P write into per-wave [32][40] tile
      const bool mask = last && (hf == tl);
#pragma unroll
      for (int mi = 0; mi < 2; ++mi) {
        const int qrow = q0 + mi * 16 + fr;
#pragma unroll
        for (int nj = 0; nj < 2; ++nj) {
          const int kvb = k0 + hf * 32 + nj * 16 + fq * 4;
          v4bf pk;
#pragma unroll
          for (int r = 0; r < 4; ++r) {
            float sv = s[mi][nj][r];
            if (mask && (kvb + r > qrow)) sv = -__builtin_inff();
            pk[r] = (__bf16)fexp2(sv - FIXMAX);
          }
          *reinterpret_cast<v4bf*>(pw + (mi * 16 + fr) * 40 + nj * 16 + fq * 4) = pk;
        }
      }

      // PV over the 32-kv half: ctx += P @ V ; row-sums += P @ ones
      v8bf pa[2];
#pragma unroll
      for (int mi = 0; mi < 2; ++mi)
        pa[mi] = *reinterpret_cast<const v8bf*>(pw + (mi * 16 + fr) * 40 + fq * 8);
      __builtin_amdgcn_s_setprio(1);
#pragma unroll
      for (int mi = 0; mi < 2; ++mi)
        csum[mi] = __builtin_amdgcn_mfma_f32_16x16x32_bf16(pa[mi], onev, csum[mi], 0, 0, 0);
#pragma unroll
      for (int nf = 0; nf < 4; ++nf)
#pragma unroll
        for (int mi = 0; mi < 2; ++mi)
          cacc[mi][nf] = __builtin_amdgcn_mfma_f32_16x16x32_bf16(pa[mi], vf[nf], cacc[mi][nf], 0, 0, 0);
      __builtin_amdgcn_s_setprio(0);
    }
    __builtin_amdgcn_sched_barrier(0);  // proven order (r5/r6): fence BEFORE the barrier
    __builtin_amdgcn_s_barrier();
  }

  // ---- combine kv-halves (additive, exact under fixed max) + epilogue ----
  __syncthreads();
  float* comb = (float*)(lds + 16384);  // P tiles dead
  float* slot = comb + (tl * 64 + lane) * 41;
  if (hf == 1) {
#pragma unroll
    for (int mi = 0; mi < 2; ++mi) {
#pragma unroll
      for (int nf = 0; nf < 4; ++nf)
#pragma unroll
        for (int r = 0; r < 4; ++r) slot[mi * 16 + nf * 4 + r] = cacc[mi][nf][r];
#pragma unroll
      for (int r = 0; r < 4; ++r) slot[32 + mi * 4 + r] = csum[mi][r];
    }
  }
  __syncthreads();
  if (hf == 0) {
#pragma unroll
    for (int mi = 0; mi < 2; ++mi) {
#pragma unroll
      for (int nf = 0; nf < 4; ++nf)
#pragma unroll
        for (int r = 0; r < 4; ++r) cacc[mi][nf][r] += slot[mi * 16 + nf * 4 + r];
#pragma unroll
      for (int r = 0; r < 4; ++r) csum[mi][r] += slot[32 + mi * 4 + r];
    }
    // normalize, sigmoid(g) gate, store ctx bf16
#pragma unroll
    for (int mi = 0; mi < 2; ++mi)
#pragma unroll
      for (int r = 0; r < 4; ++r) {
        const int grow = q0 + mi * 16 + fq * 4 + r;
        const float rl = 1.f / csum[mi][r];
#pragma unroll
        for (int nf = 0; nf < 4; ++nf) {
          const int col = hb + nf * 16 + fr;
          float vv = cacc[mi][nf][r] * rl;
          const float gt = (float)base[(size_t)grow * LD + 1024 + col];
          vv *= 1.f / (1.f + fexp2(-gt * LOG2E));
          CTX[((size_t)b * L + grow) * 1024 + col] = (__bf16)vv;
        }
      }
  }
}

extern "C" void kernel_launch(void* const* d_in, const int* in_sizes, int n_in,
                              void* d_out, int out_size, void* d_ws, size_t ws_size,
                              hipStream_t stream) {
  const float* x  = (const float*)d_in[0];
  const float* Wq = (const float*)d_in[1];
  const float* Wg = (const float*)d_in[2];
  const float* Wk = (const float*)d_in[3];
  const float* Wv = (const float*)d_in[4];
  const float* Wo = (const float*)d_in[5];
  const float* bo = (const float*)d_in[6];

  char* ws = (char*)d_ws;
  __bf16* xb  = (__bf16*)(ws);                  //  8 MB  [4096,1024]
  __bf16* w3  = (__bf16*)(ws + (8u  << 20));    //  6 MB  [3072,1024]
  __bf16* wvb = (__bf16*)(ws + (14u << 20));    //  2 MB
  __bf16* wob = (__bf16*)(ws + (16u << 20));    //  2 MB
  __bf16* qgk = (__bf16*)(ws + (18u << 20));    // 24 MB  [4096,3072]
  __bf16* vt  = (__bf16*)(ws + (42u << 20));    //  8 MB  [1024,4096]
  __bf16* ctx = (__bf16*)(ws + (50u << 20));    //  8 MB  [4096,1024]

  cvt_all_kernel<<<dim3(9216), dim3(256), 0, stream>>>(x, Wq, Wg, Wk, Wv, Wo,
                                                       xb, w3, wvb, wob);

  // QGK (768 blocks) + VT (256 blocks) in one dispatch
  proj_kernel<<<dim3(1024), dim3(256), 0, stream>>>(xb, w3, wvb, qgk, vt);

  // flash attention + gate: 1024 blocks = exact residency (4/CU)
  attn_kernel<<<dim3(1024), dim3(256), 0, stream>>>(qgk, vt, ctx);

  // out = ctx @ Wo^T + bo : M=4096, N=1024, K=1024, fp32 (BN=64 -> 512 blocks)
  gemm_bt_kernel<true, 64><<<dim3(16, 32), dim3(256), 0, stream>>>(
      ctx, wob, d_out, bo, 1024, 1024, 1024, 1024);
}

// Round 11
// 134.848 us; speedup vs baseline: 1.1844x; 1.0059x over previous
//
#include <hip/hip_runtime.h>
#include <hip/hip_bf16.h>

// Shapes: B=2, L=2048, D_IN=1024, D_OUT=1024, H=16, HD=64
// ROUND 8 VERBATIM RESUBMISSION (bisection round).
// r9/r10 both failed at marginal absmax (~1.7-2.0e-2) with attn byte-identical to r8's
// passing run; their GEMM deltas should have been bit-identical. Resubmitting the exact
// passing source distinguishes: pass -> r9/r10 deltas were buggy; fail -> attn is flaky.
// Pipeline:
//   cvt_all: x -> xb; [Wq*c, Wg, Wk] -> w3; Wv -> wvb; Wo -> wob  (c = 0.125*log2e in Wq)
//   proj:   QGK[4096,3072] = xb @ w3^T  and  VT[1024,4096] = wvb @ xb^T  (one dispatch)
//   attn:   flash attention (4-wave blocks, K LDS-dbuf, V->regs, fixed-max exp2 softmax,
//           swapped QK^T, ones-MFMA row sums, uniform residency)
//   gemm<true,64>: out[4096,1024](fp32) = ctx @ Wo^T + bo

typedef __bf16 v8bf __attribute__((ext_vector_type(8)));
typedef __bf16 v4bf __attribute__((ext_vector_type(4)));
typedef float  v4f  __attribute__((ext_vector_type(4)));

using gas_void = const __attribute__((address_space(1))) void*;
using las_void = __attribute__((address_space(3))) void*;

__device__ __forceinline__ void async_ld16(const void* g, void* l) {
  __builtin_amdgcn_global_load_lds((gas_void)g, (las_void)l, 16, 0, 0);
}
__device__ __forceinline__ float fexp2(float x) { return __builtin_amdgcn_exp2f(x); }

#define QSCALE 0.18033688011112042f  /* 0.125 * log2(e) */
#define LOG2E  1.4426950408889634f
#define FIXMAX 8.0f                   /* fixed softmax max in exp2 domain */

// ---------------- all fp32 -> bf16 conversions in one kernel ----------------
__global__ void cvt_all_kernel(const float* __restrict__ x,  const float* __restrict__ Wq,
                               const float* __restrict__ Wg, const float* __restrict__ Wk,
                               const float* __restrict__ Wv, const float* __restrict__ Wo,
                               __bf16* __restrict__ xb, __bf16* __restrict__ w3,
                               __bf16* __restrict__ wvb, __bf16* __restrict__ wob) {
  int i = blockIdx.x * 256 + threadIdx.x;  // float4 index; total 2359296
  const float* s; v4bf* d; int j; float sc = 1.f;
  if (i < 1048576)      { s = x;  d = (v4bf*)xb;           j = i; }
  else if (i < 1310720) { s = Wq; d = (v4bf*)w3;           j = i - 1048576; sc = QSCALE; }
  else if (i < 1572864) { s = Wg; d = (v4bf*)w3 + 262144;  j = i - 1310720; }
  else if (i < 1835008) { s = Wk; d = (v4bf*)w3 + 524288;  j = i - 1572864; }
  else if (i < 2097152) { s = Wv; d = (v4bf*)wvb;          j = i - 1835008; }
  else                  { s = Wo; d = (v4bf*)wob;          j = i - 2097152; }
  float4 v = reinterpret_cast<const float4*>(s)[j];
  v4bf o;
  o[0] = (__bf16)(v.x * sc); o[1] = (__bf16)(v.y * sc);
  o[2] = (__bf16)(v.z * sc); o[3] = (__bf16)(v.w * sc);
  d[j] = o;
}

// ---------------- bf16 B^T GEMM tile (m97-style), as device function ----------------
template<bool OUTF32, int BN>
__device__ __forceinline__ void gemm_tile(
    const __bf16* __restrict__ A, const __bf16* __restrict__ B,
    void* __restrict__ C, const float* __restrict__ bias,
    int K, int lda, int ldb, int ldc, int m0, int n0,
    __bf16* As, __bf16* Bs) {
  constexpr int NI = BN / 32;
  const int tid  = threadIdx.x;
  const int w    = tid >> 6;
  const int lane = tid & 63;
  const int fr   = lane & 15;
  const int fq   = lane >> 4;
  const int srow = lane >> 2;
  const int scol = lane & 3;
  const int wr = (w >> 1) * 64, wc = (w & 1) * (BN / 2);

  v4f acc[4][NI];
#pragma unroll
  for (int i = 0; i < 4; ++i)
#pragma unroll
    for (int j = 0; j < NI; ++j)
#pragma unroll
      for (int r = 0; r < 4; ++r) acc[i][j][r] = 0.f;

  for (int k0 = 0; k0 < K; k0 += 32) {
#pragma unroll
    for (int i = 0; i < 2; ++i) {
      const int c = w + i * 4;
      async_ld16(A + (size_t)(m0 + c * 16 + srow) * lda + k0 + scol * 8, (void*)(As + c * 512));
    }
#pragma unroll
    for (int i = 0; i < BN / 64; ++i) {
      const int c = w + i * 4;
      async_ld16(B + (size_t)(n0 + c * 16 + srow) * ldb + k0 + scol * 8, (void*)(Bs + c * 512));
    }
    __syncthreads();

    v8bf a[4], b[NI];
#pragma unroll
    for (int mi = 0; mi < 4; ++mi)
      a[mi] = *reinterpret_cast<const v8bf*>(As + (wr + mi * 16 + fr) * 32 + fq * 8);
#pragma unroll
    for (int ni = 0; ni < NI; ++ni)
      b[ni] = *reinterpret_cast<const v8bf*>(Bs + (wc + ni * 16 + fr) * 32 + fq * 8);
#pragma unroll
    for (int mi = 0; mi < 4; ++mi)
#pragma unroll
      for (int ni = 0; ni < NI; ++ni)
        acc[mi][ni] = __builtin_amdgcn_mfma_f32_16x16x32_bf16(a[mi], b[ni], acc[mi][ni], 0, 0, 0);
    __syncthreads();
  }

#pragma unroll
  for (int mi = 0; mi < 4; ++mi)
#pragma unroll
    for (int ni = 0; ni < NI; ++ni)
#pragma unroll
      for (int r = 0; r < 4; ++r) {
        const int row = m0 + wr + mi * 16 + fq * 4 + r;
        const int col = n0 + wc + ni * 16 + fr;
        const float v = acc[mi][ni][r];
        if (OUTF32) {
          reinterpret_cast<float*>(C)[(size_t)row * ldc + col] = v + bias[col];
        } else {
          reinterpret_cast<__bf16*>(C)[(size_t)row * ldc + col] = (__bf16)v;
        }
      }
}

// merged projection: blocks 0..767 -> QGK = xb @ w3^T ; 768..1023 -> VT = wvb @ xb^T
__global__ __launch_bounds__(256) void proj_kernel(
    const __bf16* __restrict__ xb, const __bf16* __restrict__ w3,
    const __bf16* __restrict__ wvb, __bf16* __restrict__ qgk, __bf16* __restrict__ vt) {
  __shared__ __bf16 As[128 * 32];
  __shared__ __bf16 Bs[128 * 32];
  const int bid = blockIdx.x;
  if (bid < 768) {
    gemm_tile<false, 128>(xb, w3, (void*)qgk, nullptr, 1024, 1024, 1024, 3072,
                          (bid / 24) * 128, (bid % 24) * 128, As, Bs);
  } else {
    const int t = bid - 768;
    gemm_tile<false, 128>(wvb, xb, (void*)vt, nullptr, 1024, 1024, 1024, 4096,
                          (t >> 5) * 128, (t & 31) * 128, As, Bs);
  }
}

template<bool OUTF32, int BN>
__global__ __launch_bounds__(256) void gemm_bt_kernel(
    const __bf16* __restrict__ A, const __bf16* __restrict__ B,
    void* __restrict__ C, const float* __restrict__ bias,
    int K, int lda, int ldb, int ldc) {
  __shared__ __bf16 As[128 * 32];
  __shared__ __bf16 Bs[BN * 32];
  gemm_tile<OUTF32, BN>(A, B, C, bias, K, lda, ldb, ldc,
                        blockIdx.y * 128, blockIdx.x * BN, As, Bs);
}

// ---------------- flash attention: 4-wave blocks, K in LDS, V in regs ----------------
// Block (g, bh): q-tiles {2g, 2g+1}; waves tl=w>>1 (tile), hf=w&1 (kv-half); nkt=g+1.
// bid = u*256 + v ; bh = v&31 (XCD = bh%8, 4 bh/XCD); k = v>>5;
// g(u,k) = {k, 15-k, 16+k, 31-k}[u] -> per-CU-slot work uniform (66 steps total).
__global__ __launch_bounds__(256, 4) void attn_kernel(
    const __bf16* __restrict__ QGK, const __bf16* __restrict__ VT,
    __bf16* __restrict__ CTX) {
  constexpr int LD = 3072, L = 2048;
  // LDS: [0,16384) K dbuf (2 x 8KB); [16384,37888) per-wave P [32][40]bf16 / combine (union)
  __shared__ __align__(16) char lds[37888];
  const int w = threadIdx.x >> 6, lane = threadIdx.x & 63;
  const int fr = lane & 15, fq = lane >> 4;
  const int tl = w >> 1, hf = w & 1;
  const int u = blockIdx.x >> 8, v = blockIdx.x & 255;
  const int k = v >> 5;
  const int g = (u == 0) ? k : (u == 1) ? 15 - k : (u == 2) ? 16 + k : 31 - k;
  const int bh = v & 31;
  const int b = bh >> 4, h = bh & 15, hb = h * 64;
  const int qt = 2 * g + tl, q0 = qt * 32, nkt = g + 1;
  const __bf16* base  = QGK + (size_t)b * L * LD;
  const __bf16* vbase = VT + (size_t)hb * 4096 + (size_t)b * L;
  __bf16* pw = (__bf16*)(lds + 16384 + w * 2560);

  v8bf onev;
#pragma unroll
  for (int i = 0; i < 8; ++i) onev[i] = (__bf16)1.0f;

  v8bf qf[2][2];
#pragma unroll
  for (int mi = 0; mi < 2; ++mi)
#pragma unroll
    for (int ks = 0; ks < 2; ++ks)
      qf[mi][ks] = *reinterpret_cast<const v8bf*>(
          base + (size_t)(q0 + mi * 16 + fr) * LD + hb + ks * 32 + fq * 8);

  v4f cacc[2][4], csum[2];
#pragma unroll
  for (int mi = 0; mi < 2; ++mi) {
#pragma unroll
    for (int r = 0; r < 4; ++r) csum[mi][r] = 0.f;
#pragma unroll
    for (int nf = 0; nf < 4; ++nf)
#pragma unroll
      for (int r = 0; r < 4; ++r) cacc[mi][nf][r] = 0.f;
  }

  auto stage = [&](int bi, int k0s) {
    char* bf_ = (char*)lds + bi * 8192;
#pragma unroll
    for (int i = 0; i < 2; ++i) {
      const int slot = i * 256 + w * 64 + lane;
      const int r = slot >> 3;
      const int cc = ((slot & 7) ^ (r & 7)) * 8;
      async_ld16(base + (size_t)(k0s + r) * LD + 2048 + hb + cc,
                 bf_ + (i * 256 + w * 64) * 16);
    }
  };

  stage(0, 0);
  for (int kt = 0; kt < nkt; ++kt) {
    const int k0 = kt * 64;
    const bool last = (kt == nkt - 1);
    v8bf vf[4];
#pragma unroll
    for (int nf = 0; nf < 4; ++nf)
      vf[nf] = *reinterpret_cast<const v8bf*>(
          vbase + (size_t)(nf * 16 + fr) * 4096 + k0 + hf * 32 + fq * 8);
    if (!last) {
      stage((kt + 1) & 1, k0 + 64);
      asm volatile("s_waitcnt vmcnt(6)" ::: "memory");
    } else {
      asm volatile("s_waitcnt vmcnt(4)" ::: "memory");
    }
    __builtin_amdgcn_s_barrier();
    __builtin_amdgcn_sched_barrier(0);

    if (!(last && tl == 0 && hf == 1)) {
      const __bf16* Kt = (const __bf16*)(lds + (kt & 1) * 8192);
      v8bf kf[2][2];
#pragma unroll
      for (int ks = 0; ks < 2; ++ks)
#pragma unroll
        for (int nj = 0; nj < 2; ++nj)
          kf[ks][nj] = *reinterpret_cast<const v8bf*>(
              Kt + (hf * 32 + nj * 16 + fr) * 64 + (((ks * 4 + fq) ^ (fr & 7)) * 8));

      v4f s[2][2];
#pragma unroll
      for (int mi = 0; mi < 2; ++mi)
#pragma unroll
        for (int nj = 0; nj < 2; ++nj)
#pragma unroll
          for (int r = 0; r < 4; ++r) s[mi][nj][r] = 0.f;
      __builtin_amdgcn_s_setprio(1);
#pragma unroll
      for (int ks = 0; ks < 2; ++ks)
#pragma unroll
        for (int mi = 0; mi < 2; ++mi)
#pragma unroll
          for (int nj = 0; nj < 2; ++nj)
            s[mi][nj] = __builtin_amdgcn_mfma_f32_16x16x32_bf16(
                kf[ks][nj], qf[mi][ks], s[mi][nj], 0, 0, 0);
      __builtin_amdgcn_s_setprio(0);

      const bool mask = last && (hf == tl);
#pragma unroll
      for (int mi = 0; mi < 2; ++mi) {
        const int qrow = q0 + mi * 16 + fr;
#pragma unroll
        for (int nj = 0; nj < 2; ++nj) {
          const int kvb = k0 + hf * 32 + nj * 16 + fq * 4;
          v4bf pk;
#pragma unroll
          for (int r = 0; r < 4; ++r) {
            float sv = s[mi][nj][r];
            if (mask && (kvb + r > qrow)) sv = -__builtin_inff();
            pk[r] = (__bf16)fexp2(sv - FIXMAX);
          }
          *reinterpret_cast<v4bf*>(pw + (mi * 16 + fr) * 40 + nj * 16 + fq * 4) = pk;
        }
      }

      v8bf pa[2];
#pragma unroll
      for (int mi = 0; mi < 2; ++mi)
        pa[mi] = *reinterpret_cast<const v8bf*>(pw + (mi * 16 + fr) * 40 + fq * 8);
      __builtin_amdgcn_s_setprio(1);
#pragma unroll
      for (int mi = 0; mi < 2; ++mi)
        csum[mi] = __builtin_amdgcn_mfma_f32_16x16x32_bf16(pa[mi], onev, csum[mi], 0, 0, 0);
#pragma unroll
      for (int nf = 0; nf < 4; ++nf)
#pragma unroll
        for (int mi = 0; mi < 2; ++mi)
          cacc[mi][nf] = __builtin_amdgcn_mfma_f32_16x16x32_bf16(pa[mi], vf[nf], cacc[mi][nf], 0, 0, 0);
      __builtin_amdgcn_s_setprio(0);
    }
    __builtin_amdgcn_sched_barrier(0);  // proven order (r5/r6/r8): fence BEFORE the barrier
    __builtin_amdgcn_s_barrier();
  }

  __syncthreads();
  float* comb = (float*)(lds + 16384);
  float* slot = comb + (tl * 64 + lane) * 41;
  if (hf == 1) {
#pragma unroll
    for (int mi = 0; mi < 2; ++mi) {
#pragma unroll
      for (int nf = 0; nf < 4; ++nf)
#pragma unroll
        for (int r = 0; r < 4; ++r) slot[mi * 16 + nf * 4 + r] = cacc[mi][nf][r];
#pragma unroll
      for (int r = 0; r < 4; ++r) slot[32 + mi * 4 + r] = csum[mi][r];
    }
  }
  __syncthreads();
  if (hf == 0) {
#pragma unroll
    for (int mi = 0; mi < 2; ++mi) {
#pragma unroll
      for (int nf = 0; nf < 4; ++nf)
#pragma unroll
        for (int r = 0; r < 4; ++r) cacc[mi][nf][r] += slot[mi * 16 + nf * 4 + r];
#pragma unroll
      for (int r = 0; r < 4; ++r) csum[mi][r] += slot[32 + mi * 4 + r];
    }
#pragma unroll
    for (int mi = 0; mi < 2; ++mi)
#pragma unroll
      for (int r = 0; r < 4; ++r) {
        const int grow = q0 + mi * 16 + fq * 4 + r;
        const float rl = 1.f / csum[mi][r];
#pragma unroll
        for (int nf = 0; nf < 4; ++nf) {
          const int col = hb + nf * 16 + fr;
          float vv = cacc[mi][nf][r] * rl;
          const float gt = (float)base[(size_t)grow * LD + 1024 + col];
          vv *= 1.f / (1.f + fexp2(-gt * LOG2E));
          CTX[((size_t)b * L + grow) * 1024 + col] = (__bf16)vv;
        }
      }
  }
}

extern "C" void kernel_launch(void* const* d_in, const int* in_sizes, int n_in,
                              void* d_out, int out_size, void* d_ws, size_t ws_size,
                              hipStream_t stream) {
  const float* x  = (const float*)d_in[0];
  const float* Wq = (const float*)d_in[1];
  const float* Wg = (const float*)d_in[2];
  const float* Wk = (const float*)d_in[3];
  const float* Wv = (const float*)d_in[4];
  const float* Wo = (const float*)d_in[5];
  const float* bo = (const float*)d_in[6];

  char* ws = (char*)d_ws;
  __bf16* xb  = (__bf16*)(ws);                  //  8 MB  [4096,1024]
  __bf16* w3  = (__bf16*)(ws + (8u  << 20));    //  6 MB  [3072,1024]
  __bf16* wvb = (__bf16*)(ws + (14u << 20));    //  2 MB
  __bf16* wob = (__bf16*)(ws + (16u << 20));    //  2 MB
  __bf16* qgk = (__bf16*)(ws + (18u << 20));    // 24 MB  [4096,3072]
  __bf16* vt  = (__bf16*)(ws + (42u << 20));    //  8 MB  [1024,4096]
  __bf16* ctx = (__bf16*)(ws + (50u << 20));    //  8 MB  [4096,1024]

  cvt_all_kernel<<<dim3(9216), dim3(256), 0, stream>>>(x, Wq, Wg, Wk, Wv, Wo,
                                                       xb, w3, wvb, wob);

  // QGK (768 blocks) + VT (256 blocks) in one dispatch
  proj_kernel<<<dim3(1024), dim3(256), 0, stream>>>(xb, w3, wvb, qgk, vt);

  // flash attention + gate: 1024 blocks = exact residency (4/CU)
  attn_kernel<<<dim3(1024), dim3(256), 0, stream>>>(qgk, vt, ctx);

  // out = ctx @ Wo^T + bo : M=4096, N=1024, K=1024, fp32 (BN=64 -> 512 blocks)
  gemm_bt_kernel<true, 64><<<dim3(16, 32), dim3(256), 0, stream>>>(
      ctx, wob, d_out, bo, 1024, 1024, 1024, 1024);
}

// Round 12
// 133.591 us; speedup vs baseline: 1.1955x; 1.0094x over previous
//
#include <hip/hip_runtime.h>
#include <hip/hip_bf16.h>

// Shapes: B=2, L=2048, D_IN=1024, D_OUT=1024, H=16, HD=64
// Pipeline:
//   cvt_all: x -> xb; [Wq*c, Wg, Wk] -> w3; Wv -> wvb; Wo -> wob  (c = 0.125*log2e in Wq)
//   proj:   QGK[4096,3072] = xb @ w3^T  and  VT[1024,4096] = wvb @ xb^T  (one dispatch,
//           XCD-swizzled block order)
//   attn:   flash attention (4-wave blocks, K LDS-dbuf, V->regs, fixed-max exp2 softmax,
//           swapped QK^T, ones-MFMA row sums, uniform residency)
//   gemm<true,64>: out[4096,1024](fp32) = ctx @ Wo^T + bo
// SYNC DISCIPLINE (round 12): r11 proved the raw s_barrier + counted-vmcnt loop is
// nondeterministic (same binary: absmax 0.0069 vs 0.0123) -- s_barrier is not an LLVM
// memory fence, so staging writes can cross it into the window other waves still read.
// ALL cross-wave sync is now __syncthreads() (full drain + fence). Overlap retained by
// issuing stage(next-buf) at the TOP of the compute phase: it flies during compute and
// the single end-of-iteration __syncthreads drains it. vf loads issued BEFORE stage so
// in-order vmcnt retirement of the vf-wait leaves the stage in flight.

typedef __bf16 v8bf __attribute__((ext_vector_type(8)));
typedef __bf16 v4bf __attribute__((ext_vector_type(4)));
typedef float  v4f  __attribute__((ext_vector_type(4)));

using gas_void = const __attribute__((address_space(1))) void*;
using las_void = __attribute__((address_space(3))) void*;

__device__ __forceinline__ void async_ld16(const void* g, void* l) {
  __builtin_amdgcn_global_load_lds((gas_void)g, (las_void)l, 16, 0, 0);
}
__device__ __forceinline__ float fexp2(float x) { return __builtin_amdgcn_exp2f(x); }

#define QSCALE 0.18033688011112042f  /* 0.125 * log2(e) */
#define LOG2E  1.4426950408889634f
#define FIXMAX 8.0f                   /* fixed softmax max in exp2 domain */

// ---------------- all fp32 -> bf16 conversions in one kernel ----------------
__global__ void cvt_all_kernel(const float* __restrict__ x,  const float* __restrict__ Wq,
                               const float* __restrict__ Wg, const float* __restrict__ Wk,
                               const float* __restrict__ Wv, const float* __restrict__ Wo,
                               __bf16* __restrict__ xb, __bf16* __restrict__ w3,
                               __bf16* __restrict__ wvb, __bf16* __restrict__ wob) {
  int i = blockIdx.x * 256 + threadIdx.x;  // float4 index; total 2359296
  const float* s; v4bf* d; int j; float sc = 1.f;
  if (i < 1048576)      { s = x;  d = (v4bf*)xb;           j = i; }
  else if (i < 1310720) { s = Wq; d = (v4bf*)w3;           j = i - 1048576; sc = QSCALE; }
  else if (i < 1572864) { s = Wg; d = (v4bf*)w3 + 262144;  j = i - 1310720; }
  else if (i < 1835008) { s = Wk; d = (v4bf*)w3 + 524288;  j = i - 1572864; }
  else if (i < 2097152) { s = Wv; d = (v4bf*)wvb;          j = i - 1835008; }
  else                  { s = Wo; d = (v4bf*)wob;          j = i - 2097152; }
  float4 v = reinterpret_cast<const float4*>(s)[j];
  v4bf o;
  o[0] = (__bf16)(v.x * sc); o[1] = (__bf16)(v.y * sc);
  o[2] = (__bf16)(v.z * sc); o[3] = (__bf16)(v.w * sc);
  d[j] = o;
}

// ---------------- bf16 B^T GEMM tile, BK=32 dbuf, single __syncthreads/iter ----------------
// C[m0:m0+128, n0:n0+BN] = A[m0:,:K] * B[n0:,:K]^T
// As: 2 x [128][32]; Bs: 2 x [BN][32].  stage(t+1) issued at top of compute(t); the
// end-of-iteration __syncthreads drains it (compute consumes no VMEM -> stage rides free).
template<bool OUTF32, int BN>
__device__ __forceinline__ void gemm_tile(
    const __bf16* __restrict__ A, const __bf16* __restrict__ B,
    void* __restrict__ C, const float* __restrict__ bias,
    int K, int lda, int ldb, int ldc, int m0, int n0,
    __bf16* As, __bf16* Bs) {
  constexpr int NI = BN / 32;
  const int tid  = threadIdx.x;
  const int w    = tid >> 6;
  const int lane = tid & 63;
  const int fr   = lane & 15;
  const int fq   = lane >> 4;
  const int srow = lane >> 2;
  const int scol = lane & 3;
  const int wr = (w >> 1) * 64, wc = (w & 1) * (BN / 2);

  v4f acc[4][NI];
#pragma unroll
  for (int i = 0; i < 4; ++i)
#pragma unroll
    for (int j = 0; j < NI; ++j)
#pragma unroll
      for (int r = 0; r < 4; ++r) acc[i][j][r] = 0.f;

  auto stage = [&](int bi, int k0) {
#pragma unroll
    for (int i = 0; i < 2; ++i) {
      const int c = w + i * 4;
      async_ld16(A + (size_t)(m0 + c * 16 + srow) * lda + k0 + scol * 8,
                 (void*)(As + bi * 4096 + c * 512));
    }
#pragma unroll
    for (int i = 0; i < BN / 64; ++i) {
      const int c = w + i * 4;
      async_ld16(B + (size_t)(n0 + c * 16 + srow) * ldb + k0 + scol * 8,
                 (void*)(Bs + bi * (BN * 32) + c * 512));
    }
  };

  const int nk = K >> 5;
  stage(0, 0);
  __syncthreads();
  for (int t = 0; t < nk; ++t) {
    if (t + 1 < nk) stage((t + 1) & 1, (t + 1) * 32);  // in flight during compute

    const __bf16* Ac = As + (t & 1) * 4096;
    const __bf16* Bc = Bs + (t & 1) * (BN * 32);
    v8bf a[4], b[NI];
#pragma unroll
    for (int mi = 0; mi < 4; ++mi)
      a[mi] = *reinterpret_cast<const v8bf*>(Ac + (wr + mi * 16 + fr) * 32 + fq * 8);
#pragma unroll
    for (int ni = 0; ni < NI; ++ni)
      b[ni] = *reinterpret_cast<const v8bf*>(Bc + (wc + ni * 16 + fr) * 32 + fq * 8);
    __builtin_amdgcn_s_setprio(1);
#pragma unroll
    for (int mi = 0; mi < 4; ++mi)
#pragma unroll
      for (int ni = 0; ni < NI; ++ni)
        acc[mi][ni] = __builtin_amdgcn_mfma_f32_16x16x32_bf16(a[mi], b[ni], acc[mi][ni], 0, 0, 0);
    __builtin_amdgcn_s_setprio(0);
    __syncthreads();  // drains stage(t+1); all waves done reading buf(t)
  }

#pragma unroll
  for (int mi = 0; mi < 4; ++mi)
#pragma unroll
    for (int ni = 0; ni < NI; ++ni)
#pragma unroll
      for (int r = 0; r < 4; ++r) {
        const int row = m0 + wr + mi * 16 + fq * 4 + r;
        const int col = n0 + wc + ni * 16 + fr;
        const float v = acc[mi][ni][r];
        if (OUTF32) {
          reinterpret_cast<float*>(C)[(size_t)row * ldc + col] = v + bias[col];
        } else {
          reinterpret_cast<__bf16*>(C)[(size_t)row * ldc + col] = (__bf16)v;
        }
      }
}

// merged projection, XCD-swizzled (1024 % 8 == 0 -> bijective):
// blocks 0..767 -> QGK = xb @ w3^T ; 768..1023 -> VT = wvb @ xb^T
__global__ __launch_bounds__(256) void proj_kernel(
    const __bf16* __restrict__ xb, const __bf16* __restrict__ w3,
    const __bf16* __restrict__ wvb, __bf16* __restrict__ qgk, __bf16* __restrict__ vt) {
  __shared__ __bf16 As[2 * 128 * 32];
  __shared__ __bf16 Bs[2 * 128 * 32];
  const int bid = (blockIdx.x & 7) * 128 + (blockIdx.x >> 3);
  if (bid < 768) {
    gemm_tile<false, 128>(xb, w3, (void*)qgk, nullptr, 1024, 1024, 1024, 3072,
                          (bid / 24) * 128, (bid % 24) * 128, As, Bs);
  } else {
    const int t = bid - 768;
    gemm_tile<false, 128>(wvb, xb, (void*)vt, nullptr, 1024, 1024, 1024, 4096,
                          (t >> 5) * 128, (t & 31) * 128, As, Bs);
  }
}

template<bool OUTF32, int BN>
__global__ __launch_bounds__(256) void gemm_bt_kernel(
    const __bf16* __restrict__ A, const __bf16* __restrict__ B,
    void* __restrict__ C, const float* __restrict__ bias,
    int K, int lda, int ldb, int ldc) {
  __shared__ __bf16 As[2 * 128 * 32];
  __shared__ __bf16 Bs[2 * BN * 32];
  gemm_tile<OUTF32, BN>(A, B, C, bias, K, lda, ldb, ldc,
                        blockIdx.y * 128, blockIdx.x * BN, As, Bs);
}

// ---------------- flash attention: 4-wave blocks, K in LDS, V in regs ----------------
// Block (g, bh): q-tiles {2g, 2g+1}; waves tl=w>>1 (tile), hf=w&1 (kv-half); nkt=g+1.
// bid = u*256 + v ; bh = v&31 (XCD = bh%8, 4 bh/XCD); k = v>>5;
// g(u,k) = {k, 15-k, 16+k, 31-k}[u] -> per-CU-slot work uniform (66 steps total).
// Sync: ONE __syncthreads per K-step (see header note); no raw barriers, no manual vmcnt.
__global__ __launch_bounds__(256, 4) void attn_kernel(
    const __bf16* __restrict__ QGK, const __bf16* __restrict__ VT,
    __bf16* __restrict__ CTX) {
  constexpr int LD = 3072, L = 2048;
  // LDS: [0,16384) K dbuf (2 x 8KB); [16384,37888) per-wave P [32][40]bf16 / combine (union)
  __shared__ __align__(16) char lds[37888];
  const int w = threadIdx.x >> 6, lane = threadIdx.x & 63;
  const int fr = lane & 15, fq = lane >> 4;
  const int tl = w >> 1, hf = w & 1;
  const int u = blockIdx.x >> 8, v = blockIdx.x & 255;
  const int k = v >> 5;
  const int g = (u == 0) ? k : (u == 1) ? 15 - k : (u == 2) ? 16 + k : 31 - k;
  const int bh = v & 31;
  const int b = bh >> 4, h = bh & 15, hb = h * 64;
  const int qt = 2 * g + tl, q0 = qt * 32, nkt = g + 1;
  const __bf16* base  = QGK + (size_t)b * L * LD;
  const __bf16* vbase = VT + (size_t)hb * 4096 + (size_t)b * L;
  __bf16* pw = (__bf16*)(lds + 16384 + w * 2560);

  v8bf onev;
#pragma unroll
  for (int i = 0; i < 8; ++i) onev[i] = (__bf16)1.0f;

  v8bf qf[2][2];
#pragma unroll
  for (int mi = 0; mi < 2; ++mi)
#pragma unroll
    for (int ks = 0; ks < 2; ++ks)
      qf[mi][ks] = *reinterpret_cast<const v8bf*>(
          base + (size_t)(q0 + mi * 16 + fr) * LD + hb + ks * 32 + fq * 8);

  v4f cacc[2][4], csum[2];
#pragma unroll
  for (int mi = 0; mi < 2; ++mi) {
#pragma unroll
    for (int r = 0; r < 4; ++r) csum[mi][r] = 0.f;
#pragma unroll
    for (int nf = 0; nf < 4; ++nf)
#pragma unroll
      for (int r = 0; r < 4; ++r) cacc[mi][nf][r] = 0.f;
  }

  auto stage = [&](int bi, int k0s) {
    char* bf_ = (char*)lds + bi * 8192;
#pragma unroll
    for (int i = 0; i < 2; ++i) {
      const int slot = i * 256 + w * 64 + lane;
      const int r = slot >> 3;
      const int cc = ((slot & 7) ^ (r & 7)) * 8;
      async_ld16(base + (size_t)(k0s + r) * LD + 2048 + hb + cc,
                 bf_ + (i * 256 + w * 64) * 16);
    }
  };

  stage(0, 0);
  __syncthreads();  // buf0 staged (drains qf loads too; their data is in regs)
  for (int kt = 0; kt < nkt; ++kt) {
    const int k0 = kt * 64;
    const bool last = (kt == nkt - 1);
    // vf BEFORE stage: in-order vmcnt retirement of the PV vf-wait then leaves stage in flight
    v8bf vf[4];
#pragma unroll
    for (int nf = 0; nf < 4; ++nf)
      vf[nf] = *reinterpret_cast<const v8bf*>(
          vbase + (size_t)(nf * 16 + fr) * 4096 + k0 + hf * 32 + fq * 8);
    if (!last) stage((kt + 1) & 1, k0 + 64);  // flies during compute below

    if (!(last && tl == 0 && hf == 1)) {  // even tile: upper kv-half fully masked at diag
      const __bf16* Kt = (const __bf16*)(lds + (kt & 1) * 8192);
      v8bf kf[2][2];
#pragma unroll
      for (int ks = 0; ks < 2; ++ks)
#pragma unroll
        for (int nj = 0; nj < 2; ++nj)
          kf[ks][nj] = *reinterpret_cast<const v8bf*>(
              Kt + (hf * 32 + nj * 16 + fr) * 64 + (((ks * 4 + fq) ^ (fr & 7)) * 8));

      v4f s[2][2];
#pragma unroll
      for (int mi = 0; mi < 2; ++mi)
#pragma unroll
        for (int nj = 0; nj < 2; ++nj)
#pragma unroll
          for (int r = 0; r < 4; ++r) s[mi][nj][r] = 0.f;
      __builtin_amdgcn_s_setprio(1);
#pragma unroll
      for (int ks = 0; ks < 2; ++ks)
#pragma unroll
        for (int mi = 0; mi < 2; ++mi)
#pragma unroll
          for (int nj = 0; nj < 2; ++nj)
            s[mi][nj] = __builtin_amdgcn_mfma_f32_16x16x32_bf16(
                kf[ks][nj], qf[mi][ks], s[mi][nj], 0, 0, 0);
      __builtin_amdgcn_s_setprio(0);

      const bool mask = last && (hf == tl);
#pragma unroll
      for (int mi = 0; mi < 2; ++mi) {
        const int qrow = q0 + mi * 16 + fr;
#pragma unroll
        for (int nj = 0; nj < 2; ++nj) {
          const int kvb = k0 + hf * 32 + nj * 16 + fq * 4;
          v4bf pk;
#pragma unroll
          for (int r = 0; r < 4; ++r) {
            float sv = s[mi][nj][r];
            if (mask && (kvb + r > qrow)) sv = -__builtin_inff();
            pk[r] = (__bf16)fexp2(sv - FIXMAX);
          }
          *reinterpret_cast<v4bf*>(pw + (mi * 16 + fr) * 40 + nj * 16 + fq * 4) = pk;
        }
      }

      v8bf pa[2];
#pragma unroll
      for (int mi = 0; mi < 2; ++mi)
        pa[mi] = *reinterpret_cast<const v8bf*>(pw + (mi * 16 + fr) * 40 + fq * 8);
      __builtin_amdgcn_s_setprio(1);
#pragma unroll
      for (int mi = 0; mi < 2; ++mi)
        csum[mi] = __builtin_amdgcn_mfma_f32_16x16x32_bf16(pa[mi], onev, csum[mi], 0, 0, 0);
#pragma unroll
      for (int nf = 0; nf < 4; ++nf)
#pragma unroll
        for (int mi = 0; mi < 2; ++mi)
          cacc[mi][nf] = __builtin_amdgcn_mfma_f32_16x16x32_bf16(pa[mi], vf[nf], cacc[mi][nf], 0, 0, 0);
      __builtin_amdgcn_s_setprio(0);
    }
    __syncthreads();  // drains stage(kt+1); all waves done reading buf(kt)
  }

  // ---- combine kv-halves (additive, exact under fixed max) + epilogue ----
  float* comb = (float*)(lds + 16384);  // P tiles dead (loop ended with __syncthreads)
  float* slot = comb + (tl * 64 + lane) * 41;
  if (hf == 1) {
#pragma unroll
    for (int mi = 0; mi < 2; ++mi) {
#pragma unroll
      for (int nf = 0; nf < 4; ++nf)
#pragma unroll
        for (int r = 0; r < 4; ++r) slot[mi * 16 + nf * 4 + r] = cacc[mi][nf][r];
#pragma unroll
      for (int r = 0; r < 4; ++r) slot[32 + mi * 4 + r] = csum[mi][r];
    }
  }
  __syncthreads();
  if (hf == 0) {
#pragma unroll
    for (int mi = 0; mi < 2; ++mi) {
#pragma unroll
      for (int nf = 0; nf < 4; ++nf)
#pragma unroll
        for (int r = 0; r < 4; ++r) cacc[mi][nf][r] += slot[mi * 16 + nf * 4 + r];
#pragma unroll
      for (int r = 0; r < 4; ++r) csum[mi][r] += slot[32 + mi * 4 + r];
    }
#pragma unroll
    for (int mi = 0; mi < 2; ++mi)
#pragma unroll
      for (int r = 0; r < 4; ++r) {
        const int grow = q0 + mi * 16 + fq * 4 + r;
        const float rl = 1.f / csum[mi][r];
#pragma unroll
        for (int nf = 0; nf < 4; ++nf) {
          const int col = hb + nf * 16 + fr;
          float vv = cacc[mi][nf][r] * rl;
          const float gt = (float)base[(size_t)grow * LD + 1024 + col];
          vv *= 1.f / (1.f + fexp2(-gt * LOG2E));
          CTX[((size_t)b * L + grow) * 1024 + col] = (__bf16)vv;
        }
      }
  }
}

extern "C" void kernel_launch(void* const* d_in, const int* in_sizes, int n_in,
                              void* d_out, int out_size, void* d_ws, size_t ws_size,
                              hipStream_t stream) {
  const float* x  = (const float*)d_in[0];
  const float* Wq = (const float*)d_in[1];
  const float* Wg = (const float*)d_in[2];
  const float* Wk = (const float*)d_in[3];
  const float* Wv = (const float*)d_in[4];
  const float* Wo = (const float*)d_in[5];
  const float* bo = (const float*)d_in[6];

  char* ws = (char*)d_ws;
  __bf16* xb  = (__bf16*)(ws);                  //  8 MB  [4096,1024]
  __bf16* w3  = (__bf16*)(ws + (8u  << 20));    //  6 MB  [3072,1024]
  __bf16* wvb = (__bf16*)(ws + (14u << 20));    //  2 MB
  __bf16* wob = (__bf16*)(ws + (16u << 20));    //  2 MB
  __bf16* qgk = (__bf16*)(ws + (18u << 20));    // 24 MB  [4096,3072]
  __bf16* vt  = (__bf16*)(ws + (42u << 20));    //  8 MB  [1024,4096]
  __bf16* ctx = (__bf16*)(ws + (50u << 20));    //  8 MB  [4096,1024]

  cvt_all_kernel<<<dim3(9216), dim3(256), 0, stream>>>(x, Wq, Wg, Wk, Wv, Wo,
                                                       xb, w3, wvb, wob);

  // QGK (768 blocks) + VT (256 blocks) in one dispatch, XCD-swizzled
  proj_kernel<<<dim3(1024), dim3(256), 0, stream>>>(xb, w3, wvb, qgk, vt);

  // flash attention + gate: 1024 blocks = exact residency (4/CU)
  attn_kernel<<<dim3(1024), dim3(256), 0, stream>>>(qgk, vt, ctx);

  // out = ctx @ Wo^T + bo : M=4096, N=1024, K=1024, fp32 (BN=64 -> 512 blocks)
  gemm_bt_kernel<true, 64><<<dim3(16, 32), dim3(256), 0, stream>>>(
      ctx, wob, d_out, bo, 1024, 1024, 1024, 1024);
}

// Round 13
// 120.219 us; speedup vs baseline: 1.3285x; 1.1112x over previous
//
#include <hip/hip_runtime.h>
#include <hip/hip_bf16.h>

// Shapes: B=2, L=2048, D_IN=1024, D_OUT=1024, H=16, HD=64
// Pipeline:
//   cvt_all: x -> xb; [Wq*c, Wg, Wk] -> w3; Wv -> wvb; Wo -> wob  (c = 0.125*log2e in Wq)
//   proj:   QGK[4096,3072] = xb @ w3^T  and  VT[1024,4096] = wvb @ xb^T  (one dispatch)
//   attn:   flash attention (byte-identical to round 12: deterministic __syncthreads-only
//           sync, 4-wave blocks, K LDS-dbuf, V->regs, fixed-max exp2 softmax, swapped
//           QK^T, ones-MFMA row sums, uniform residency)
//   gemm<true,64>: out[4096,1024](fp32) = ctx @ Wo^T + bo
// GEMM (round 13): BK=64, XOR col-block swizzle (LDS[r][cb]=G[r][cb^(r&7)]) -> b128 reads
// at the bank floor (r12 unswizzled BK=32 was ~4x over floor, 4.19M conflicts) and half
// the barrier-drain count. Sync is __syncthreads-only (r11/r12 lesson: raw s_barrier +
// counted vmcnt is nondeterministic). No XCD swizzle on proj (r12: FETCH 48->59MB, -9%).

typedef __bf16 v8bf __attribute__((ext_vector_type(8)));
typedef __bf16 v4bf __attribute__((ext_vector_type(4)));
typedef float  v4f  __attribute__((ext_vector_type(4)));

using gas_void = const __attribute__((address_space(1))) void*;
using las_void = __attribute__((address_space(3))) void*;

__device__ __forceinline__ void async_ld16(const void* g, void* l) {
  __builtin_amdgcn_global_load_lds((gas_void)g, (las_void)l, 16, 0, 0);
}
__device__ __forceinline__ float fexp2(float x) { return __builtin_amdgcn_exp2f(x); }

#define QSCALE 0.18033688011112042f  /* 0.125 * log2(e) */
#define LOG2E  1.4426950408889634f
#define FIXMAX 8.0f                   /* fixed softmax max in exp2 domain */

// ---------------- all fp32 -> bf16 conversions in one kernel ----------------
__global__ void cvt_all_kernel(const float* __restrict__ x,  const float* __restrict__ Wq,
                               const float* __restrict__ Wg, const float* __restrict__ Wk,
                               const float* __restrict__ Wv, const float* __restrict__ Wo,
                               __bf16* __restrict__ xb, __bf16* __restrict__ w3,
                               __bf16* __restrict__ wvb, __bf16* __restrict__ wob) {
  const int i0 = blockIdx.x * 512 + threadIdx.x;  // 2 float4 per thread; total 2359296
#pragma unroll
  for (int rep = 0; rep < 2; ++rep) {
    const int i = i0 + rep * 256;
    const float* s; v4bf* d; int j; float sc = 1.f;
    if (i < 1048576)      { s = x;  d = (v4bf*)xb;           j = i; }
    else if (i < 1310720) { s = Wq; d = (v4bf*)w3;           j = i - 1048576; sc = QSCALE; }
    else if (i < 1572864) { s = Wg; d = (v4bf*)w3 + 262144;  j = i - 1310720; }
    else if (i < 1835008) { s = Wk; d = (v4bf*)w3 + 524288;  j = i - 1572864; }
    else if (i < 2097152) { s = Wv; d = (v4bf*)wvb;          j = i - 1835008; }
    else                  { s = Wo; d = (v4bf*)wob;          j = i - 2097152; }
    float4 v = reinterpret_cast<const float4*>(s)[j];
    v4bf o;
    o[0] = (__bf16)(v.x * sc); o[1] = (__bf16)(v.y * sc);
    o[2] = (__bf16)(v.z * sc); o[3] = (__bf16)(v.w * sc);
    d[j] = o;
  }
}

// ---------------- bf16 B^T GEMM tile, BK=64, XOR-swizzled LDS ----------------
// C[m0:m0+128, n0:n0+BN] = A[m0:,:K] * B[n0:,:K]^T
// As: [128][64] bf16 (16 KB); Bs: [BN][64].  LDS[row][cb] = global[row][cb ^ (row&7)]
// (swizzle pre-applied on the global source address; read XOR-corrects -> bank-floor).
template<bool OUTF32, int BN>
__device__ __forceinline__ void gemm_tile(
    const __bf16* __restrict__ A, const __bf16* __restrict__ B,
    void* __restrict__ C, const float* __restrict__ bias,
    int K, int lda, int ldb, int ldc, int m0, int n0,
    __bf16* As, __bf16* Bs) {
  constexpr int NI = BN / 32;
  const int tid  = threadIdx.x;
  const int w    = tid >> 6;
  const int lane = tid & 63;
  const int fr   = lane & 15;
  const int fq   = lane >> 4;
  const int sr   = lane >> 3;   // row within 8-row chunk
  const int sc   = lane & 7;    // dst col-block (8 bf16 = 16 B)
  const int wr = (w >> 1) * 64, wc = (w & 1) * (BN / 2);

  v4f acc[4][NI];
#pragma unroll
  for (int i = 0; i < 4; ++i)
#pragma unroll
    for (int j = 0; j < NI; ++j)
#pragma unroll
      for (int r = 0; r < 4; ++r) acc[i][j][r] = 0.f;

  for (int k0 = 0; k0 < K; k0 += 64) {
    // A: 16 chunks x 8 rows (wave w -> chunks w, w+4, w+8, w+12); source pre-swizzled
#pragma unroll
    for (int i = 0; i < 4; ++i) {
      const int c = w + i * 4;
      async_ld16(A + (size_t)(m0 + c * 8 + sr) * lda + k0 + ((sc ^ sr) * 8),
                 (void*)(As + c * 512));
    }
#pragma unroll
    for (int i = 0; i < BN / 32; ++i) {
      const int c = w + i * 4;
      async_ld16(B + (size_t)(n0 + c * 8 + sr) * ldb + k0 + ((sc ^ sr) * 8),
                 (void*)(Bs + c * 512));
    }
    __syncthreads();

#pragma unroll
    for (int ks = 0; ks < 2; ++ks) {
      v8bf a[4], b[NI];
#pragma unroll
      for (int mi = 0; mi < 4; ++mi)
        a[mi] = *reinterpret_cast<const v8bf*>(
            As + (wr + mi * 16 + fr) * 64 + (((ks * 4 + fq) ^ (fr & 7)) * 8));
#pragma unroll
      for (int ni = 0; ni < NI; ++ni)
        b[ni] = *reinterpret_cast<const v8bf*>(
            Bs + (wc + ni * 16 + fr) * 64 + (((ks * 4 + fq) ^ (fr & 7)) * 8));
      __builtin_amdgcn_s_setprio(1);
#pragma unroll
      for (int mi = 0; mi < 4; ++mi)
#pragma unroll
        for (int ni = 0; ni < NI; ++ni)
          acc[mi][ni] = __builtin_amdgcn_mfma_f32_16x16x32_bf16(a[mi], b[ni], acc[mi][ni], 0, 0, 0);
      __builtin_amdgcn_s_setprio(0);
    }
    __syncthreads();
  }

#pragma unroll
  for (int mi = 0; mi < 4; ++mi)
#pragma unroll
    for (int ni = 0; ni < NI; ++ni)
#pragma unroll
      for (int r = 0; r < 4; ++r) {
        const int row = m0 + wr + mi * 16 + fq * 4 + r;
        const int col = n0 + wc + ni * 16 + fr;
        const float v = acc[mi][ni][r];
        if (OUTF32) {
          reinterpret_cast<float*>(C)[(size_t)row * ldc + col] = v + bias[col];
        } else {
          reinterpret_cast<__bf16*>(C)[(size_t)row * ldc + col] = (__bf16)v;
        }
      }
}

// merged projection: blocks 0..767 -> QGK = xb @ w3^T ; 768..1023 -> VT = wvb @ xb^T
__global__ __launch_bounds__(256) void proj_kernel(
    const __bf16* __restrict__ xb, const __bf16* __restrict__ w3,
    const __bf16* __restrict__ wvb, __bf16* __restrict__ qgk, __bf16* __restrict__ vt) {
  __shared__ __bf16 As[128 * 64];
  __shared__ __bf16 Bs[128 * 64];
  const int bid = blockIdx.x;
  if (bid < 768) {
    gemm_tile<false, 128>(xb, w3, (void*)qgk, nullptr, 1024, 1024, 1024, 3072,
                          (bid / 24) * 128, (bid % 24) * 128, As, Bs);
  } else {
    const int t = bid - 768;
    gemm_tile<false, 128>(wvb, xb, (void*)vt, nullptr, 1024, 1024, 1024, 4096,
                          (t >> 5) * 128, (t & 31) * 128, As, Bs);
  }
}

template<bool OUTF32, int BN>
__global__ __launch_bounds__(256) void gemm_bt_kernel(
    const __bf16* __restrict__ A, const __bf16* __restrict__ B,
    void* __restrict__ C, const float* __restrict__ bias,
    int K, int lda, int ldb, int ldc) {
  __shared__ __bf16 As[128 * 64];
  __shared__ __bf16 Bs[BN * 64];
  gemm_tile<OUTF32, BN>(A, B, C, bias, K, lda, ldb, ldc,
                        blockIdx.y * 128, blockIdx.x * BN, As, Bs);
}

// ---------------- flash attention: 4-wave blocks, K in LDS, V in regs ----------------
// (byte-identical to round 12 — deterministic, absmax 0.0039, steady-state ~29 us)
__global__ __launch_bounds__(256, 4) void attn_kernel(
    const __bf16* __restrict__ QGK, const __bf16* __restrict__ VT,
    __bf16* __restrict__ CTX) {
  constexpr int LD = 3072, L = 2048;
  // LDS: [0,16384) K dbuf (2 x 8KB); [16384,37888) per-wave P [32][40]bf16 / combine (union)
  __shared__ __align__(16) char lds[37888];
  const int w = threadIdx.x >> 6, lane = threadIdx.x & 63;
  const int fr = lane & 15, fq = lane >> 4;
  const int tl = w >> 1, hf = w & 1;
  const int u = blockIdx.x >> 8, v = blockIdx.x & 255;
  const int k = v >> 5;
  const int g = (u == 0) ? k : (u == 1) ? 15 - k : (u == 2) ? 16 + k : 31 - k;
  const int bh = v & 31;
  const int b = bh >> 4, h = bh & 15, hb = h * 64;
  const int qt = 2 * g + tl, q0 = qt * 32, nkt = g + 1;
  const __bf16* base  = QGK + (size_t)b * L * LD;
  const __bf16* vbase = VT + (size_t)hb * 4096 + (size_t)b * L;
  __bf16* pw = (__bf16*)(lds + 16384 + w * 2560);

  v8bf onev;
#pragma unroll
  for (int i = 0; i < 8; ++i) onev[i] = (__bf16)1.0f;

  v8bf qf[2][2];
#pragma unroll
  for (int mi = 0; mi < 2; ++mi)
#pragma unroll
    for (int ks = 0; ks < 2; ++ks)
      qf[mi][ks] = *reinterpret_cast<const v8bf*>(
          base + (size_t)(q0 + mi * 16 + fr) * LD + hb + ks * 32 + fq * 8);

  v4f cacc[2][4], csum[2];
#pragma unroll
  for (int mi = 0; mi < 2; ++mi) {
#pragma unroll
    for (int r = 0; r < 4; ++r) csum[mi][r] = 0.f;
#pragma unroll
    for (int nf = 0; nf < 4; ++nf)
#pragma unroll
      for (int r = 0; r < 4; ++r) cacc[mi][nf][r] = 0.f;
  }

  auto stage = [&](int bi, int k0s) {
    char* bf_ = (char*)lds + bi * 8192;
#pragma unroll
    for (int i = 0; i < 2; ++i) {
      const int slot = i * 256 + w * 64 + lane;
      const int r = slot >> 3;
      const int cc = ((slot & 7) ^ (r & 7)) * 8;
      async_ld16(base + (size_t)(k0s + r) * LD + 2048 + hb + cc,
                 bf_ + (i * 256 + w * 64) * 16);
    }
  };

  stage(0, 0);
  __syncthreads();  // buf0 staged (drains qf loads too; their data is in regs)
  for (int kt = 0; kt < nkt; ++kt) {
    const int k0 = kt * 64;
    const bool last = (kt == nkt - 1);
    // vf BEFORE stage: in-order vmcnt retirement of the PV vf-wait then leaves stage in flight
    v8bf vf[4];
#pragma unroll
    for (int nf = 0; nf < 4; ++nf)
      vf[nf] = *reinterpret_cast<const v8bf*>(
          vbase + (size_t)(nf * 16 + fr) * 4096 + k0 + hf * 32 + fq * 8);
    if (!last) stage((kt + 1) & 1, k0 + 64);  // flies during compute below

    if (!(last && tl == 0 && hf == 1)) {  // even tile: upper kv-half fully masked at diag
      const __bf16* Kt = (const __bf16*)(lds + (kt & 1) * 8192);
      v8bf kf[2][2];
#pragma unroll
      for (int ks = 0; ks < 2; ++ks)
#pragma unroll
        for (int nj = 0; nj < 2; ++nj)
          kf[ks][nj] = *reinterpret_cast<const v8bf*>(
              Kt + (hf * 32 + nj * 16 + fr) * 64 + (((ks * 4 + fq) ^ (fr & 7)) * 8));

      v4f s[2][2];
#pragma unroll
      for (int mi = 0; mi < 2; ++mi)
#pragma unroll
        for (int nj = 0; nj < 2; ++nj)
#pragma unroll
          for (int r = 0; r < 4; ++r) s[mi][nj][r] = 0.f;
      __builtin_amdgcn_s_setprio(1);
#pragma unroll
      for (int ks = 0; ks < 2; ++ks)
#pragma unroll
        for (int mi = 0; mi < 2; ++mi)
#pragma unroll
          for (int nj = 0; nj < 2; ++nj)
            s[mi][nj] = __builtin_amdgcn_mfma_f32_16x16x32_bf16(
                kf[ks][nj], qf[mi][ks], s[mi][nj], 0, 0, 0);
      __builtin_amdgcn_s_setprio(0);

      const bool mask = last && (hf == tl);
#pragma unroll
      for (int mi = 0; mi < 2; ++mi) {
        const int qrow = q0 + mi * 16 + fr;
#pragma unroll
        for (int nj = 0; nj < 2; ++nj) {
          const int kvb = k0 + hf * 32 + nj * 16 + fq * 4;
          v4bf pk;
#pragma unroll
          for (int r = 0; r < 4; ++r) {
            float sv = s[mi][nj][r];
            if (mask && (kvb + r > qrow)) sv = -__builtin_inff();
            pk[r] = (__bf16)fexp2(sv - FIXMAX);
          }
          *reinterpret_cast<v4bf*>(pw + (mi * 16 + fr) * 40 + nj * 16 + fq * 4) = pk;
        }
      }

      v8bf pa[2];
#pragma unroll
      for (int mi = 0; mi < 2; ++mi)
        pa[mi] = *reinterpret_cast<const v8bf*>(pw + (mi * 16 + fr) * 40 + fq * 8);
      __builtin_amdgcn_s_setprio(1);
#pragma unroll
      for (int mi = 0; mi < 2; ++mi)
        csum[mi] = __builtin_amdgcn_mfma_f32_16x16x32_bf16(pa[mi], onev, csum[mi], 0, 0, 0);
#pragma unroll
      for (int nf = 0; nf < 4; ++nf)
#pragma unroll
        for (int mi = 0; mi < 2; ++mi)
          cacc[mi][nf] = __builtin_amdgcn_mfma_f32_16x16x32_bf16(pa[mi], vf[nf], cacc[mi][nf], 0, 0, 0);
      __builtin_amdgcn_s_setprio(0);
    }
    __syncthreads();  // drains stage(kt+1); all waves done reading buf(kt)
  }

  // ---- combine kv-halves (additive, exact under fixed max) + epilogue ----
  float* comb = (float*)(lds + 16384);  // P tiles dead (loop ended with __syncthreads)
  float* slot = comb + (tl * 64 + lane) * 41;
  if (hf == 1) {
#pragma unroll
    for (int mi = 0; mi < 2; ++mi) {
#pragma unroll
      for (int nf = 0; nf < 4; ++nf)
#pragma unroll
        for (int r = 0; r < 4; ++r) slot[mi * 16 + nf * 4 + r] = cacc[mi][nf][r];
#pragma unroll
      for (int r = 0; r < 4; ++r) slot[32 + mi * 4 + r] = csum[mi][r];
    }
  }
  __syncthreads();
  if (hf == 0) {
#pragma unroll
    for (int mi = 0; mi < 2; ++mi) {
#pragma unroll
      for (int nf = 0; nf < 4; ++nf)
#pragma unroll
        for (int r = 0; r < 4; ++r) cacc[mi][nf][r] += slot[mi * 16 + nf * 4 + r];
#pragma unroll
      for (int r = 0; r < 4; ++r) csum[mi][r] += slot[32 + mi * 4 + r];
    }
#pragma unroll
    for (int mi = 0; mi < 2; ++mi)
#pragma unroll
      for (int r = 0; r < 4; ++r) {
        const int grow = q0 + mi * 16 + fq * 4 + r;
        const float rl = 1.f / csum[mi][r];
#pragma unroll
        for (int nf = 0; nf < 4; ++nf) {
          const int col = hb + nf * 16 + fr;
          float vv = cacc[mi][nf][r] * rl;
          const float gt = (float)base[(size_t)grow * LD + 1024 + col];
          vv *= 1.f / (1.f + fexp2(-gt * LOG2E));
          CTX[((size_t)b * L + grow) * 1024 + col] = (__bf16)vv;
        }
      }
  }
}

extern "C" void kernel_launch(void* const* d_in, const int* in_sizes, int n_in,
                              void* d_out, int out_size, void* d_ws, size_t ws_size,
                              hipStream_t stream) {
  const float* x  = (const float*)d_in[0];
  const float* Wq = (const float*)d_in[1];
  const float* Wg = (const float*)d_in[2];
  const float* Wk = (const float*)d_in[3];
  const float* Wv = (const float*)d_in[4];
  const float* Wo = (const float*)d_in[5];
  const float* bo = (const float*)d_in[6];

  char* ws = (char*)d_ws;
  __bf16* xb  = (__bf16*)(ws);                  //  8 MB  [4096,1024]
  __bf16* w3  = (__bf16*)(ws + (8u  << 20));    //  6 MB  [3072,1024]
  __bf16* wvb = (__bf16*)(ws + (14u << 20));    //  2 MB
  __bf16* wob = (__bf16*)(ws + (16u << 20));    //  2 MB
  __bf16* qgk = (__bf16*)(ws + (18u << 20));    // 24 MB  [4096,3072]
  __bf16* vt  = (__bf16*)(ws + (42u << 20));    //  8 MB  [1024,4096]
  __bf16* ctx = (__bf16*)(ws + (50u << 20));    //  8 MB  [4096,1024]

  cvt_all_kernel<<<dim3(4608), dim3(256), 0, stream>>>(x, Wq, Wg, Wk, Wv, Wo,
                                                       xb, w3, wvb, wob);

  // QGK (768 blocks) + VT (256 blocks) in one dispatch
  proj_kernel<<<dim3(1024), dim3(256), 0, stream>>>(xb, w3, wvb, qgk, vt);

  // flash attention + gate: 1024 blocks = exact residency (4/CU)
  attn_kernel<<<dim3(1024), dim3(256), 0, stream>>>(qgk, vt, ctx);

  // out = ctx @ Wo^T + bo : M=4096, N=1024, K=1024, fp32 (BN=64 -> 512 blocks)
  gemm_bt_kernel<true, 64><<<dim3(16, 32), dim3(256), 0, stream>>>(
      ctx, wob, d_out, bo, 1024, 1024, 1024, 1024);
}

// Round 14
// 118.014 us; speedup vs baseline: 1.3533x; 1.0187x over previous
//
#include <hip/hip_runtime.h>
#include <hip/hip_bf16.h>

// Shapes: B=2, L=2048, D_IN=1024, D_OUT=1024, H=16, HD=64
// Pipeline:
//   cvt_all: x -> xb; [Wq*c, Wg, Wk] -> w3; Wv -> wvb; Wo -> wob  (c = 0.125*log2e in Wq)
//   proj:   QGK[4096,3072] = xb @ w3^T  and  VT[1024,4096] = wvb @ xb^T  (one dispatch)
//   attn:   flash attention (byte-identical to r12/r13: deterministic __syncthreads-only)
//   gemm<true,64>: out[4096,1024](fp32) = ctx @ Wo^T + bo
// GEMM (round 14): r12-proven dbuf schedule (stage(t+1) at top of compute(t), ONE
// __syncthreads per iter -- race-free by construction) + r13-proven BK=64 XOR swizzle
// (bank conflicts 0). K accumulation order unchanged -> bit-identical numerics to r13.
// Sync remains __syncthreads-only everywhere (r11 lesson: raw s_barrier + counted vmcnt
// is nondeterministic at HIP source level).

typedef __bf16 v8bf __attribute__((ext_vector_type(8)));
typedef __bf16 v4bf __attribute__((ext_vector_type(4)));
typedef float  v4f  __attribute__((ext_vector_type(4)));

using gas_void = const __attribute__((address_space(1))) void*;
using las_void = __attribute__((address_space(3))) void*;

__device__ __forceinline__ void async_ld16(const void* g, void* l) {
  __builtin_amdgcn_global_load_lds((gas_void)g, (las_void)l, 16, 0, 0);
}
__device__ __forceinline__ float fexp2(float x) { return __builtin_amdgcn_exp2f(x); }

#define QSCALE 0.18033688011112042f  /* 0.125 * log2(e) */
#define LOG2E  1.4426950408889634f
#define FIXMAX 8.0f                   /* fixed softmax max in exp2 domain */

// ---------------- all fp32 -> bf16 conversions in one kernel ----------------
__global__ void cvt_all_kernel(const float* __restrict__ x,  const float* __restrict__ Wq,
                               const float* __restrict__ Wg, const float* __restrict__ Wk,
                               const float* __restrict__ Wv, const float* __restrict__ Wo,
                               __bf16* __restrict__ xb, __bf16* __restrict__ w3,
                               __bf16* __restrict__ wvb, __bf16* __restrict__ wob) {
  const int i0 = blockIdx.x * 512 + threadIdx.x;  // 2 float4 per thread; total 2359296
#pragma unroll
  for (int rep = 0; rep < 2; ++rep) {
    const int i = i0 + rep * 256;
    const float* s; v4bf* d; int j; float sc = 1.f;
    if (i < 1048576)      { s = x;  d = (v4bf*)xb;           j = i; }
    else if (i < 1310720) { s = Wq; d = (v4bf*)w3;           j = i - 1048576; sc = QSCALE; }
    else if (i < 1572864) { s = Wg; d = (v4bf*)w3 + 262144;  j = i - 1310720; }
    else if (i < 1835008) { s = Wk; d = (v4bf*)w3 + 524288;  j = i - 1572864; }
    else if (i < 2097152) { s = Wv; d = (v4bf*)wvb;          j = i - 1835008; }
    else                  { s = Wo; d = (v4bf*)wob;          j = i - 2097152; }
    float4 v = reinterpret_cast<const float4*>(s)[j];
    v4bf o;
    o[0] = (__bf16)(v.x * sc); o[1] = (__bf16)(v.y * sc);
    o[2] = (__bf16)(v.z * sc); o[3] = (__bf16)(v.w * sc);
    d[j] = o;
  }
}

// ---------------- bf16 B^T GEMM tile, BK=64 dbuf, XOR-swizzled LDS ----------------
// C[m0:m0+128, n0:n0+BN] = A[m0:,:K] * B[n0:,:K]^T
// As: 2 x [128][64] bf16; Bs: 2 x [BN][64].  LDS[row][cb] = global[row][cb ^ (row&7)]
// (swizzle pre-applied on the global source; read XOR-corrects -> bank-floor, 0 conflicts).
// stage(t+1) issued at top of compute(t); end-of-iter __syncthreads drains it.
template<bool OUTF32, int BN>
__device__ __forceinline__ void gemm_tile(
    const __bf16* __restrict__ A, const __bf16* __restrict__ B,
    void* __restrict__ C, const float* __restrict__ bias,
    int K, int lda, int ldb, int ldc, int m0, int n0,
    __bf16* As, __bf16* Bs) {
  constexpr int NI = BN / 32;
  const int tid  = threadIdx.x;
  const int w    = tid >> 6;
  const int lane = tid & 63;
  const int fr   = lane & 15;
  const int fq   = lane >> 4;
  const int sr   = lane >> 3;   // row within 8-row chunk
  const int sc   = lane & 7;    // dst col-block (8 bf16 = 16 B)
  const int wr = (w >> 1) * 64, wc = (w & 1) * (BN / 2);

  v4f acc[4][NI];
#pragma unroll
  for (int i = 0; i < 4; ++i)
#pragma unroll
    for (int j = 0; j < NI; ++j)
#pragma unroll
      for (int r = 0; r < 4; ++r) acc[i][j][r] = 0.f;

  // stage K-step k0 into buffer bi (A: 4 loads, B: BN/32 loads per thread)
  auto stage = [&](int bi, int k0) {
#pragma unroll
    for (int i = 0; i < 4; ++i) {
      const int c = w + i * 4;
      async_ld16(A + (size_t)(m0 + c * 8 + sr) * lda + k0 + ((sc ^ sr) * 8),
                 (void*)(As + bi * 8192 + c * 512));
    }
#pragma unroll
    for (int i = 0; i < BN / 32; ++i) {
      const int c = w + i * 4;
      async_ld16(B + (size_t)(n0 + c * 8 + sr) * ldb + k0 + ((sc ^ sr) * 8),
                 (void*)(Bs + bi * (BN * 64) + c * 512));
    }
  };

  const int nk = K >> 6;
  stage(0, 0);
  __syncthreads();
  for (int t = 0; t < nk; ++t) {
    if (t + 1 < nk) stage((t + 1) & 1, (t + 1) * 64);  // flies during compute below

    const __bf16* Ac = As + (t & 1) * 8192;
    const __bf16* Bc = Bs + (t & 1) * (BN * 64);
#pragma unroll
    for (int ks = 0; ks < 2; ++ks) {
      v8bf a[4], b[NI];
#pragma unroll
      for (int mi = 0; mi < 4; ++mi)
        a[mi] = *reinterpret_cast<const v8bf*>(
            Ac + (wr + mi * 16 + fr) * 64 + (((ks * 4 + fq) ^ (fr & 7)) * 8));
#pragma unroll
      for (int ni = 0; ni < NI; ++ni)
        b[ni] = *reinterpret_cast<const v8bf*>(
            Bc + (wc + ni * 16 + fr) * 64 + (((ks * 4 + fq) ^ (fr & 7)) * 8));
      __builtin_amdgcn_s_setprio(1);
#pragma unroll
      for (int mi = 0; mi < 4; ++mi)
#pragma unroll
        for (int ni = 0; ni < NI; ++ni)
          acc[mi][ni] = __builtin_amdgcn_mfma_f32_16x16x32_bf16(a[mi], b[ni], acc[mi][ni], 0, 0, 0);
      __builtin_amdgcn_s_setprio(0);
    }
    __syncthreads();  // drains stage(t+1); all waves done reading buf(t)
  }

#pragma unroll
  for (int mi = 0; mi < 4; ++mi)
#pragma unroll
    for (int ni = 0; ni < NI; ++ni)
#pragma unroll
      for (int r = 0; r < 4; ++r) {
        const int row = m0 + wr + mi * 16 + fq * 4 + r;
        const int col = n0 + wc + ni * 16 + fr;
        const float v = acc[mi][ni][r];
        if (OUTF32) {
          reinterpret_cast<float*>(C)[(size_t)row * ldc + col] = v + bias[col];
        } else {
          reinterpret_cast<__bf16*>(C)[(size_t)row * ldc + col] = (__bf16)v;
        }
      }
}

// merged projection: blocks 0..767 -> QGK = xb @ w3^T ; 768..1023 -> VT = wvb @ xb^T
__global__ __launch_bounds__(256) void proj_kernel(
    const __bf16* __restrict__ xb, const __bf16* __restrict__ w3,
    const __bf16* __restrict__ wvb, __bf16* __restrict__ qgk, __bf16* __restrict__ vt) {
  __shared__ __bf16 As[2 * 128 * 64];
  __shared__ __bf16 Bs[2 * 128 * 64];
  const int bid = blockIdx.x;
  if (bid < 768) {
    gemm_tile<false, 128>(xb, w3, (void*)qgk, nullptr, 1024, 1024, 1024, 3072,
                          (bid / 24) * 128, (bid % 24) * 128, As, Bs);
  } else {
    const int t = bid - 768;
    gemm_tile<false, 128>(wvb, xb, (void*)vt, nullptr, 1024, 1024, 1024, 4096,
                          (t >> 5) * 128, (t & 31) * 128, As, Bs);
  }
}

template<bool OUTF32, int BN>
__global__ __launch_bounds__(256) void gemm_bt_kernel(
    const __bf16* __restrict__ A, const __bf16* __restrict__ B,
    void* __restrict__ C, const float* __restrict__ bias,
    int K, int lda, int ldb, int ldc) {
  __shared__ __bf16 As[2 * 128 * 64];
  __shared__ __bf16 Bs[2 * BN * 64];
  gemm_tile<OUTF32, BN>(A, B, C, bias, K, lda, ldb, ldc,
                        blockIdx.y * 128, blockIdx.x * BN, As, Bs);
}

// ---------------- flash attention: 4-wave blocks, K in LDS, V in regs ----------------
// (byte-identical to round 12/13 — deterministic, absmax 0.0039, steady-state ~29 us)
__global__ __launch_bounds__(256, 4) void attn_kernel(
    const __bf16* __restrict__ QGK, const __bf16* __restrict__ VT,
    __bf16* __restrict__ CTX) {
  constexpr int LD = 3072, L = 2048;
  // LDS: [0,16384) K dbuf (2 x 8KB); [16384,37888) per-wave P [32][40]bf16 / combine (union)
  __shared__ __align__(16) char lds[37888];
  const int w = threadIdx.x >> 6, lane = threadIdx.x & 63;
  const int fr = lane & 15, fq = lane >> 4;
  const int tl = w >> 1, hf = w & 1;
  const int u = blockIdx.x >> 8, v = blockIdx.x & 255;
  const int k = v >> 5;
  const int g = (u == 0) ? k : (u == 1) ? 15 - k : (u == 2) ? 16 + k : 31 - k;
  const int bh = v & 31;
  const int b = bh >> 4, h = bh & 15, hb = h * 64;
  const int qt = 2 * g + tl, q0 = qt * 32, nkt = g + 1;
  const __bf16* base  = QGK + (size_t)b * L * LD;
  const __bf16* vbase = VT + (size_t)hb * 4096 + (size_t)b * L;
  __bf16* pw = (__bf16*)(lds + 16384 + w * 2560);

  v8bf onev;
#pragma unroll
  for (int i = 0; i < 8; ++i) onev[i] = (__bf16)1.0f;

  v8bf qf[2][2];
#pragma unroll
  for (int mi = 0; mi < 2; ++mi)
#pragma unroll
    for (int ks = 0; ks < 2; ++ks)
      qf[mi][ks] = *reinterpret_cast<const v8bf*>(
          base + (size_t)(q0 + mi * 16 + fr) * LD + hb + ks * 32 + fq * 8);

  v4f cacc[2][4], csum[2];
#pragma unroll
  for (int mi = 0; mi < 2; ++mi) {
#pragma unroll
    for (int r = 0; r < 4; ++r) csum[mi][r] = 0.f;
#pragma unroll
    for (int nf = 0; nf < 4; ++nf)
#pragma unroll
      for (int r = 0; r < 4; ++r) cacc[mi][nf][r] = 0.f;
  }

  auto stage = [&](int bi, int k0s) {
    char* bf_ = (char*)lds + bi * 8192;
#pragma unroll
    for (int i = 0; i < 2; ++i) {
      const int slot = i * 256 + w * 64 + lane;
      const int r = slot >> 3;
      const int cc = ((slot & 7) ^ (r & 7)) * 8;
      async_ld16(base + (size_t)(k0s + r) * LD + 2048 + hb + cc,
                 bf_ + (i * 256 + w * 64) * 16);
    }
  };

  stage(0, 0);
  __syncthreads();  // buf0 staged (drains qf loads too; their data is in regs)
  for (int kt = 0; kt < nkt; ++kt) {
    const int k0 = kt * 64;
    const bool last = (kt == nkt - 1);
    // vf BEFORE stage: in-order vmcnt retirement of the PV vf-wait then leaves stage in flight
    v8bf vf[4];
#pragma unroll
    for (int nf = 0; nf < 4; ++nf)
      vf[nf] = *reinterpret_cast<const v8bf*>(
          vbase + (size_t)(nf * 16 + fr) * 4096 + k0 + hf * 32 + fq * 8);
    if (!last) stage((kt + 1) & 1, k0 + 64);  // flies during compute below

    if (!(last && tl == 0 && hf == 1)) {  // even tile: upper kv-half fully masked at diag
      const __bf16* Kt = (const __bf16*)(lds + (kt & 1) * 8192);
      v8bf kf[2][2];
#pragma unroll
      for (int ks = 0; ks < 2; ++ks)
#pragma unroll
        for (int nj = 0; nj < 2; ++nj)
          kf[ks][nj] = *reinterpret_cast<const v8bf*>(
              Kt + (hf * 32 + nj * 16 + fr) * 64 + (((ks * 4 + fq) ^ (fr & 7)) * 8));

      v4f s[2][2];
#pragma unroll
      for (int mi = 0; mi < 2; ++mi)
#pragma unroll
        for (int nj = 0; nj < 2; ++nj)
#pragma unroll
          for (int r = 0; r < 4; ++r) s[mi][nj][r] = 0.f;
      __builtin_amdgcn_s_setprio(1);
#pragma unroll
      for (int ks = 0; ks < 2; ++ks)
#pragma unroll
        for (int mi = 0; mi < 2; ++mi)
#pragma unroll
          for (int nj = 0; nj < 2; ++nj)
            s[mi][nj] = __builtin_amdgcn_mfma_f32_16x16x32_bf16(
                kf[ks][nj], qf[mi][ks], s[mi][nj], 0, 0, 0);
      __builtin_amdgcn_s_setprio(0);

      const bool mask = last && (hf == tl);
#pragma unroll
      for (int mi = 0; mi < 2; ++mi) {
        const int qrow = q0 + mi * 16 + fr;
#pragma unroll
        for (int nj = 0; nj < 2; ++nj) {
          const int kvb = k0 + hf * 32 + nj * 16 + fq * 4;
          v4bf pk;
#pragma unroll
          for (int r = 0; r < 4; ++r) {
            float sv = s[mi][nj][r];
            if (mask && (kvb + r > qrow)) sv = -__builtin_inff();
            pk[r] = (__bf16)fexp2(sv - FIXMAX);
          }
          *reinterpret_cast<v4bf*>(pw + (mi * 16 + fr) * 40 + nj * 16 + fq * 4) = pk;
        }
      }

      v8bf pa[2];
#pragma unroll
      for (int mi = 0; mi < 2; ++mi)
        pa[mi] = *reinterpret_cast<const v8bf*>(pw + (mi * 16 + fr) * 40 + fq * 8);
      __builtin_amdgcn_s_setprio(1);
#pragma unroll
      for (int mi = 0; mi < 2; ++mi)
        csum[mi] = __builtin_amdgcn_mfma_f32_16x16x32_bf16(pa[mi], onev, csum[mi], 0, 0, 0);
#pragma unroll
      for (int nf = 0; nf < 4; ++nf)
#pragma unroll
        for (int mi = 0; mi < 2; ++mi)
          cacc[mi][nf] = __builtin_amdgcn_mfma_f32_16x16x32_bf16(pa[mi], vf[nf], cacc[mi][nf], 0, 0, 0);
      __builtin_amdgcn_s_setprio(0);
    }
    __syncthreads();  // drains stage(kt+1); all waves done reading buf(kt)
  }

  // ---- combine kv-halves (additive, exact under fixed max) + epilogue ----
  float* comb = (float*)(lds + 16384);  // P tiles dead (loop ended with __syncthreads)
  float* slot = comb + (tl * 64 + lane) * 41;
  if (hf == 1) {
#pragma unroll
    for (int mi = 0; mi < 2; ++mi) {
#pragma unroll
      for (int nf = 0; nf < 4; ++nf)
#pragma unroll
        for (int r = 0; r < 4; ++r) slot[mi * 16 + nf * 4 + r] = cacc[mi][nf][r];
#pragma unroll
      for (int r = 0; r < 4; ++r) slot[32 + mi * 4 + r] = csum[mi][r];
    }
  }
  __syncthreads();
  if (hf == 0) {
#pragma unroll
    for (int mi = 0; mi < 2; ++mi) {
#pragma unroll
      for (int nf = 0; nf < 4; ++nf)
#pragma unroll
        for (int r = 0; r < 4; ++r) cacc[mi][nf][r] += slot[mi * 16 + nf * 4 + r];
#pragma unroll
      for (int r = 0; r < 4; ++r) csum[mi][r] += slot[32 + mi * 4 + r];
    }
#pragma unroll
    for (int mi = 0; mi < 2; ++mi)
#pragma unroll
      for (int r = 0; r < 4; ++r) {
        const int grow = q0 + mi * 16 + fq * 4 + r;
        const float rl = 1.f / csum[mi][r];
#pragma unroll
        for (int nf = 0; nf < 4; ++nf) {
          const int col = hb + nf * 16 + fr;
          float vv = cacc[mi][nf][r] * rl;
          const float gt = (float)base[(size_t)grow * LD + 1024 + col];
          vv *= 1.f / (1.f + fexp2(-gt * LOG2E));
          CTX[((size_t)b * L + grow) * 1024 + col] = (__bf16)vv;
        }
      }
  }
}

extern "C" void kernel_launch(void* const* d_in, const int* in_sizes, int n_in,
                              void* d_out, int out_size, void* d_ws, size_t ws_size,
                              hipStream_t stream) {
  const float* x  = (const float*)d_in[0];
  const float* Wq = (const float*)d_in[1];
  const float* Wg = (const float*)d_in[2];
  const float* Wk = (const float*)d_in[3];
  const float* Wv = (const float*)d_in[4];
  const float* Wo = (const float*)d_in[5];
  const float* bo = (const float*)d_in[6];

  char* ws = (char*)d_ws;
  __bf16* xb  = (__bf16*)(ws);                  //  8 MB  [4096,1024]
  __bf16* w3  = (__bf16*)(ws + (8u  << 20));    //  6 MB  [3072,1024]
  __bf16* wvb = (__bf16*)(ws + (14u << 20));    //  2 MB
  __bf16* wob = (__bf16*)(ws + (16u << 20));    //  2 MB
  __bf16* qgk = (__bf16*)(ws + (18u << 20));    // 24 MB  [4096,3072]
  __bf16* vt  = (__bf16*)(ws + (42u << 20));    //  8 MB  [1024,4096]
  __bf16* ctx = (__bf16*)(ws + (50u << 20));    //  8 MB  [4096,1024]

  cvt_all_kernel<<<dim3(4608), dim3(256), 0, stream>>>(x, Wq, Wg, Wk, Wv, Wo,
                                                       xb, w3, wvb, wob);

  // QGK (768 blocks) + VT (256 blocks) in one dispatch
  proj_kernel<<<dim3(1024), dim3(256), 0, stream>>>(xb, w3, wvb, qgk, vt);

  // flash attention + gate: 1024 blocks = exact residency (4/CU)
  attn_kernel<<<dim3(1024), dim3(256), 0, stream>>>(qgk, vt, ctx);

  // out = ctx @ Wo^T + bo : M=4096, N=1024, K=1024, fp32 (BN=64 -> 512 blocks)
  gemm_bt_kernel<true, 64><<<dim3(16, 32), dim3(256), 0, stream>>>(
      ctx, wob, d_out, bo, 1024, 1024, 1024, 1024);
}